// Round 3
// baseline (21140.744 us; speedup 1.0000x reference)
//
#include <hip/hip_runtime.h>
#include <hip/hip_cooperative_groups.h>
#include <math.h>

namespace cg = cooperative_groups;

#define NTOK 50257
#define NPC  225
#define NCLS 224
#define NH   1024
#define G4   4096
#define TSTEPS 128
#define BB   64
#define NN   8192

__device__ __forceinline__ float sigmf(float x){ return 1.0f/(1.0f+expf(-x)); }

// ---------------- embedding gather: X[n][:] = emb_W[ids[n]][:] ----------------
__global__ void k_embed(const int* __restrict__ ids, const float* __restrict__ embW,
                        float* __restrict__ X){
  int n = blockIdx.x;
  int t = threadIdx.x;
  const float4* s = (const float4*)(embW + (size_t)ids[n]*NH);
  float4* d = (float4*)(X + (size_t)n*NH);
  d[t] = s[t];
}

// ---------------- C[M=4096][Nd] = A[M][1024] * B[Nd][1024]^T + (bi[m]+bh[m]) ----------------
__global__ __launch_bounds__(256) void k_gemm_nt(
    const float* __restrict__ A, const float* __restrict__ B,
    const float* __restrict__ bi, const float* __restrict__ bh,
    float* __restrict__ C, int Nd)
{
  __shared__ float As[32][68];
  __shared__ float Bs[32][68];
  int m0 = blockIdx.x*64, n0 = blockIdx.y*64;
  int t = threadIdx.x;
  int tm = (t&15)*4, tn = (t>>4)*4;
  int lr = t>>3, lk = (t&7)*4;
  float acc[4][4] = {{0.f}};
  for (int k0=0;k0<NH;k0+=32){
    float4 a0 = *(const float4*)(A + (size_t)(m0+lr)*NH + k0+lk);
    float4 a1 = *(const float4*)(A + (size_t)(m0+lr+32)*NH + k0+lk);
    float4 b0 = *(const float4*)(B + (size_t)(n0+lr)*NH + k0+lk);
    float4 b1 = *(const float4*)(B + (size_t)(n0+lr+32)*NH + k0+lk);
    __syncthreads();
    As[lk+0][lr]=a0.x; As[lk+1][lr]=a0.y; As[lk+2][lr]=a0.z; As[lk+3][lr]=a0.w;
    As[lk+0][lr+32]=a1.x; As[lk+1][lr+32]=a1.y; As[lk+2][lr+32]=a1.z; As[lk+3][lr+32]=a1.w;
    Bs[lk+0][lr]=b0.x; Bs[lk+1][lr]=b0.y; Bs[lk+2][lr]=b0.z; Bs[lk+3][lr]=b0.w;
    Bs[lk+0][lr+32]=b1.x; Bs[lk+1][lr+32]=b1.y; Bs[lk+2][lr+32]=b1.z; Bs[lk+3][lr+32]=b1.w;
    __syncthreads();
    #pragma unroll 8
    for (int kk=0;kk<32;kk++){
      float4 av = *(const float4*)&As[kk][tm];
      float4 bv = *(const float4*)&Bs[kk][tn];
      acc[0][0] += av.x*bv.x; acc[0][1] += av.x*bv.y; acc[0][2] += av.x*bv.z; acc[0][3] += av.x*bv.w;
      acc[1][0] += av.y*bv.x; acc[1][1] += av.y*bv.y; acc[1][2] += av.y*bv.z; acc[1][3] += av.y*bv.w;
      acc[2][0] += av.z*bv.x; acc[2][1] += av.z*bv.y; acc[2][2] += av.z*bv.z; acc[2][3] += av.z*bv.w;
      acc[3][0] += av.w*bv.x; acc[3][1] += av.w*bv.y; acc[3][2] += av.w*bv.z; acc[3][3] += av.w*bv.w;
    }
  }
  #pragma unroll
  for (int i=0;i<4;i++){
    int m = m0+tm+i;
    float bias = bi[m]+bh[m];
    float4 o = make_float4(acc[i][0]+bias, acc[i][1]+bias, acc[i][2]+bias, acc[i][3]+bias);
    *(float4*)(C + (size_t)m*Nd + n0+tn) = o;
  }
}

// ---------------- cooperative LSTM recurrence for one layer ----------------
// 256 blocks; block jj owns hidden cols [jj*4, jj*4+4): 16 W_hh rows in LDS.
// h staged coalesced global->LDS in 4 chunks of 256 k (64 KB each), reg-prefetched.
// Compute mapping: thread t = (r = t&15 gate-row, bg = t>>4 -> batches bg*4..+3).
__global__ __launch_bounds__(256,1) void k_rec(
    const float* __restrict__ GT, const float* __restrict__ Wh,
    const float* __restrict__ h0, const float* __restrict__ c0,
    float* __restrict__ hb, float* __restrict__ Y,
    float* __restrict__ hN, float* __restrict__ cN)
{
  cg::grid_group grid = cg::this_grid();
  __shared__ float wlds[16][NH+4];     // pad -> 2-way banks max
  __shared__ float hs[64][260];        // one 256-k chunk of h, padded
  __shared__ float glds[64][20];       // gate exchange
  __shared__ float hvals[64][5];       // h store transpose
  int jj = blockIdx.x, t = threadIdx.x;
  for (int rr=0;rr<16;rr++){
    int grow = (rr>>2)*NH + jj*4 + (rr&3);
    *(float4*)&wlds[rr][t*4] = *(const float4*)(Wh + (size_t)grow*NH + t*4);
  }
  // state-update mapping
  int b = t&63, cc = t>>6;
  int hc = jj*4 + cc;
  // compute mapping
  int r = t&15, bg = t>>4;
  int g = r>>2, col = r&3;
  size_t gtrow = (size_t)(g*NH + jj*4 + col)*NN;

  float creg = c0[b*NH + hc];
  hb[b*NH + hc] = h0[b*NH + hc];     // state buffer 0
  grid.sync();

  for (int st=0; st<TSTEPS; st++){
    const float* hcur = hb + (size_t)(st&1)*BB*NH;
    float*       hnxt = hb + (size_t)((st+1)&1)*BB*NH;
    const float4* hcur4 = (const float4*)hcur;

    // gate-bias loads issued early (latency hidden under chunk compute)
    float gt0 = GT[gtrow + st*64 + bg*4 + 0];
    float gt1 = GT[gtrow + st*64 + bg*4 + 1];
    float gt2 = GT[gtrow + st*64 + bg*4 + 2];
    float gt3 = GT[gtrow + st*64 + bg*4 + 3];

    float acc0=0.f, acc1=0.f, acc2=0.f, acc3=0.f;
    // chunk = 64 rows x 64 float4 = 4096 float4; 16 per thread.
    // flat = q*256+t -> row = flat>>6, col4 = flat&63 (one 1KB row per wave-load)
    float4 sreg[16];
    #pragma unroll
    for (int q=0;q<16;q++){
      int flat = q*256 + t;
      sreg[q] = hcur4[(flat>>6)*256 + 0*64 + (flat&63)];
    }
    for (int c=0;c<4;c++){
      #pragma unroll
      for (int q=0;q<16;q++){
        int flat = q*256 + t;
        *(float4*)&hs[flat>>6][(flat&63)*4] = sreg[q];
      }
      if (c<3){
        #pragma unroll
        for (int q=0;q<16;q++){
          int flat = q*256 + t;
          sreg[q] = hcur4[(flat>>6)*256 + (c+1)*64 + (flat&63)];
        }
      }
      __syncthreads();                      // hs chunk c fully written
      const float* wrow = &wlds[r][c*256];
      const float* h0p = &hs[bg*4+0][0];
      const float* h1p = &hs[bg*4+1][0];
      const float* h2p = &hs[bg*4+2][0];
      const float* h3p = &hs[bg*4+3][0];
      #pragma unroll 4
      for (int k=0;k<256;k+=4){
        float4 w4 = *(const float4*)(wrow+k);
        float4 x0 = *(const float4*)(h0p+k);
        float4 x1 = *(const float4*)(h1p+k);
        float4 x2 = *(const float4*)(h2p+k);
        float4 x3 = *(const float4*)(h3p+k);
        acc0 += w4.x*x0.x + w4.y*x0.y + w4.z*x0.z + w4.w*x0.w;
        acc1 += w4.x*x1.x + w4.y*x1.y + w4.z*x1.z + w4.w*x1.w;
        acc2 += w4.x*x2.x + w4.y*x2.y + w4.z*x2.z + w4.w*x2.w;
        acc3 += w4.x*x3.x + w4.y*x3.y + w4.z*x3.z + w4.w*x3.w;
      }
      __syncthreads();                      // done reading chunk c
    }
    // exchange gates
    glds[bg*4+0][r] = acc0 + gt0;
    glds[bg*4+1][r] = acc1 + gt1;
    glds[bg*4+2][r] = acc2 + gt2;
    glds[bg*4+3][r] = acc3 + gt3;
    __syncthreads();
    float gi = glds[b][0*4+cc];
    float gf = glds[b][1*4+cc];
    float gg = glds[b][2*4+cc];
    float go = glds[b][3*4+cc];
    float cnew = sigmf(gf)*creg + sigmf(gi)*tanhf(gg);
    creg = cnew;
    float hv = sigmf(go)*tanhf(cnew);
    hvals[b][cc] = hv;
    if (st == TSTEPS-1){ hN[b*NH+hc] = hv; cN[b*NH+hc] = creg; }
    __syncthreads();
    // transposed store of the 64x4 h tile
    {
      int sb = t>>2, sc = t&3;
      float v = hvals[sb][sc];
      int n = st*BB + sb;
      hnxt[sb*NH + jj*4 + sc] = v;
      Y[(size_t)n*NH + jj*4 + sc] = v;
    }
    grid.sync();
  }
}

// ---------------- top logits: C[NN][224] = X[NN][1024] @ W[1024][224] + b ----------------
__global__ __launch_bounds__(256) void k_gemm_top(
    const float* __restrict__ X, const float* __restrict__ W,
    const float* __restrict__ bias, float* __restrict__ C)
{
  __shared__ float Xs[32][68];
  __shared__ float Ws[32][36];
  int n0 = blockIdx.x*64, c0 = blockIdx.y*32;
  int t = threadIdx.x;
  int tm = (t&15)*4;   // n offset
  int tn = (t>>4)*2;   // c offset
  int lr = t>>3, lk = (t&7)*4;
  float acc[4][2] = {{0.f}};
  for (int k0=0;k0<NH;k0+=32){
    float4 x0 = *(const float4*)(X + (size_t)(n0+lr)*NH + k0+lk);
    float4 x1 = *(const float4*)(X + (size_t)(n0+lr+32)*NH + k0+lk);
    float4 wv = *(const float4*)(W + (size_t)(k0 + (t>>3))*NCLS + c0 + (t&7)*4);
    __syncthreads();
    Xs[lk+0][lr]=x0.x; Xs[lk+1][lr]=x0.y; Xs[lk+2][lr]=x0.z; Xs[lk+3][lr]=x0.w;
    Xs[lk+0][lr+32]=x1.x; Xs[lk+1][lr+32]=x1.y; Xs[lk+2][lr+32]=x1.z; Xs[lk+3][lr+32]=x1.w;
    *(float4*)&Ws[t>>3][(t&7)*4] = wv;
    __syncthreads();
    #pragma unroll 8
    for (int kk=0;kk<32;kk++){
      float4 av = *(const float4*)&Xs[kk][tm];
      float2 bv = *(const float2*)&Ws[kk][tn];
      acc[0][0] += av.x*bv.x; acc[0][1] += av.x*bv.y;
      acc[1][0] += av.y*bv.x; acc[1][1] += av.y*bv.y;
      acc[2][0] += av.z*bv.x; acc[2][1] += av.z*bv.y;
      acc[3][0] += av.w*bv.x; acc[3][1] += av.w*bv.y;
    }
  }
  float bz0 = bias[c0+tn], bz1 = bias[c0+tn+1];
  #pragma unroll
  for (int i=0;i<4;i++){
    float2 o = make_float2(acc[i][0]+bz0, acc[i][1]+bz1);
    *(float2*)(C + (size_t)(n0+tm+i)*NCLS + c0+tn) = o;
  }
}

// ---------------- per-row top softmax pick ----------------
__global__ void k_top_pick(const float* __restrict__ TL, const int* __restrict__ tg,
                           float* __restrict__ ptop){
  int n = blockIdx.x*4 + (threadIdx.x>>6);
  int lane = threadIdx.x&63;
  const float* row = TL + (size_t)n*NCLS;
  float v[4]; float m = -1e30f;
  #pragma unroll
  for (int q=0;q<4;q++){ int c = lane + q*64; v[q] = (c<NCLS)? row[c] : -1e30f; m = fmaxf(m, v[q]); }
  for (int o=32;o;o>>=1) m = fmaxf(m, __shfl_xor(m,o));
  float s = 0.f;
  #pragma unroll
  for (int q=0;q<4;q++){ int c = lane + q*64; if (c<NCLS) s += expf(v[q]-m); }
  for (int o=32;o;o>>=1) s += __shfl_xor(s,o);
  if (lane==0){ int pt = tg[n]/NPC; ptop[n] = expf(row[pt]-m)/s; }
}

// ---------------- class bucketing ----------------
__global__ void k_zero(int* cnt, int* cur){ int t=threadIdx.x; if(t<NCLS){cnt[t]=0; cur[t]=0;} }
__global__ void k_hist(const int* __restrict__ tg, int* cnt){
  int n = blockIdx.x*256+threadIdx.x;
  if (n<NN) atomicAdd(&cnt[tg[n]/NPC],1);
}
__global__ void k_scan(const int* __restrict__ cnt, int* __restrict__ off){
  if (threadIdx.x==0 && blockIdx.x==0){ int a=0; for(int c=0;c<NCLS;c++){ off[c]=a; a+=cnt[c]; } off[NCLS]=a; }
}
__global__ void k_scatter(const int* __restrict__ tg, const int* __restrict__ off,
                          int* cur, int* __restrict__ perm){
  int n = blockIdx.x*256+threadIdx.x;
  if (n<NN){ int c = tg[n]/NPC; int p = atomicAdd(&cur[c],1); perm[off[c]+p] = n; }
}

// ---------------- per-class bottom GEMM + softmax pick + final product ----------------
__global__ __launch_bounds__(256) void k_bot(
    const float* __restrict__ X, const float* __restrict__ botW, const float* __restrict__ botb,
    const int* __restrict__ tg, const int* __restrict__ off, const int* __restrict__ perm,
    const float* __restrict__ ptop, float* __restrict__ outP)
{
  int cls = blockIdx.x;
  int s = off[cls], e = off[cls+1];
  if (s>=e) return;
  __shared__ float xs[16][NH];
  __shared__ float lg[16][228];
  int t = threadIdx.x;
  const float* Wc = botW + (size_t)cls*NH*NPC;
  for (int base=s; base<e; base+=16){
    int nr = min(16, e-base);
    __syncthreads();
    for (int r=0;r<nr;r++){
      int n = perm[base+r];
      *(float4*)&xs[r][t*4] = *(const float4*)(X + (size_t)n*NH + t*4);
    }
    __syncthreads();
    if (t < NPC){
      float acc[16];
      #pragma unroll
      for (int r=0;r<16;r++) acc[r]=0.f;
      for (int k=0;k<NH;k+=2){
        float w0 = Wc[(size_t)k*NPC + t];
        float w1 = Wc[(size_t)(k+1)*NPC + t];
        #pragma unroll
        for (int r=0;r<16;r++){
          float2 x2 = *(const float2*)&xs[r][k];
          acc[r] += x2.x*w0 + x2.y*w1;
        }
      }
      float bb = botb[(size_t)cls*NPC + t];
      for (int r=0;r<nr;r++) lg[r][t] = acc[r] + bb;
    }
    __syncthreads();
    int wv = t>>6, lane = t&63;
    for (int r=wv; r<nr; r+=4){
      float v[4]; float m=-1e30f;
      #pragma unroll
      for (int q=0;q<4;q++){ int c = lane+q*64; v[q] = (c<NPC)? lg[r][c] : -1e30f; m=fmaxf(m,v[q]); }
      for (int o=32;o;o>>=1) m=fmaxf(m,__shfl_xor(m,o));
      float ss=0.f;
      #pragma unroll
      for (int q=0;q<4;q++){ int c = lane+q*64; if (c<NPC) ss += expf(v[q]-m); }
      for (int o=32;o;o>>=1) ss += __shfl_xor(ss,o);
      if (lane==0){
        int n = perm[base+r]; int pb = tg[n]%NPC;
        outP[n] = ptop[n]*expf(lg[r][pb]-m)/ss;
      }
    }
  }
}

extern "C" void kernel_launch(void* const* d_in, const int* in_sizes, int n_in,
                              void* d_out, int out_size, void* d_ws, size_t ws_size,
                              hipStream_t stream)
{
  const int*   ids  = (const int*)d_in[0];
  const int*   tg   = (const int*)d_in[1];
  const float* h0   = (const float*)d_in[2];
  const float* c0   = (const float*)d_in[3];
  const float* embW = (const float*)d_in[4];
  const float* Wih  = (const float*)d_in[5];
  const float* Whh  = (const float*)d_in[6];
  const float* bih  = (const float*)d_in[7];
  const float* bhh  = (const float*)d_in[8];
  const float* topW = (const float*)d_in[9];
  const float* topb = (const float*)d_in[10];
  const float* botW = (const float*)d_in[11];
  const float* botb = (const float*)d_in[12];
  float* out = (float*)d_out;

  float* X  = (float*)d_ws;                    // [NN][NH]
  float* Yb = X  + (size_t)NN*NH;              // [NN][NH]
  float* GT = Yb + (size_t)NN*NH;              // [G4][NN]
  float* hb = GT + (size_t)G4*NN;              // [2][BB][NH]
  float* TL = hb + 2*(size_t)BB*NH;            // [NN][NCLS]
  float* pt = TL + (size_t)NN*NCLS;            // [NN]
  int* cnt  = (int*)(pt + NN);
  int* off  = cnt + NCLS;
  int* cur  = off + NCLS + 1;
  int* perm = cur + NCLS;

  k_embed<<<NN,256,0,stream>>>(ids, embW, X);

  for (int l=0; l<2; l++){
    const float* A   = Wih + (size_t)l*G4*NH;
    const float* Wl  = Whh + (size_t)l*G4*NH;
    const float* bi  = bih + (size_t)l*G4;
    const float* bh  = bhh + (size_t)l*G4;
    const float* Bx  = (l==0)? X : Yb;
    float*       Yo  = (l==0)? Yb : X;
    k_gemm_nt<<<dim3(64,128),256,0,stream>>>(A, Bx, bi, bh, GT, NN);
    const float* h0l = h0 + (size_t)l*BB*NH;
    const float* c0l = c0 + (size_t)l*BB*NH;
    float* hNl = out + NN + (size_t)l*BB*NH;
    float* cNl = out + NN + 2*(size_t)BB*NH + (size_t)l*BB*NH;
    void* args[] = { (void*)&GT, (void*)&Wl, (void*)&h0l, (void*)&c0l,
                     (void*)&hb, (void*)&Yo, (void*)&hNl, (void*)&cNl };
    hipLaunchCooperativeKernel((void*)k_rec, dim3(256), dim3(256), args, 0u, stream);
  }

  // X now holds the layer-1 output sequence [NN][NH]
  k_gemm_top<<<dim3(128,7),256,0,stream>>>(X, topW, topb, TL);
  k_top_pick<<<NN/4,256,0,stream>>>(TL, tg, pt);
  k_zero<<<1,256,0,stream>>>(cnt, cur);
  k_hist<<<NN/256,256,0,stream>>>(tg, cnt);
  k_scan<<<1,1,0,stream>>>(cnt, off);
  k_scatter<<<NN/256,256,0,stream>>>(tg, off, cur, perm);
  k_bot<<<NCLS,256,0,stream>>>(X, botW, botb, tg, off, perm, pt, out);
}

// Round 6
// 20997.154 us; speedup vs baseline: 1.0068x; 1.0068x over previous
//
#include <hip/hip_runtime.h>
#include <math.h>

#define NTOK 50257
#define NPC  225
#define NCLS 224
#define NH   1024
#define G4   4096
#define TSTEPS 128
#define BB   64
#define NN   8192

__device__ __forceinline__ float sigmf(float x){ return 1.0f/(1.0f+expf(-x)); }

__device__ __forceinline__ void gl2lds16(const float* g, float* l){
  __builtin_amdgcn_global_load_lds(
      (const __attribute__((address_space(1))) unsigned int*)(g),
      (__attribute__((address_space(3))) unsigned int*)(l), 16, 0, 0);
}

// device-scope grid barrier (grid co-resident by construction: 1 block/CU x 256)
__device__ __forceinline__ void gbar(unsigned* cnt, unsigned target){
  __threadfence();            // release my stores to device scope (drains vm/lgkm too)
  __syncthreads();
  if (threadIdx.x==0){
    __hip_atomic_fetch_add(cnt, 1u, __ATOMIC_RELEASE, __HIP_MEMORY_SCOPE_AGENT);
    while (__hip_atomic_load(cnt, __ATOMIC_ACQUIRE, __HIP_MEMORY_SCOPE_AGENT) < target)
      __builtin_amdgcn_s_sleep(1);
  }
  __syncthreads();
  __threadfence();            // acquire: invalidate stale cache lines
}

// ---------------- embedding gather ----------------
__global__ void k_embed(const int* __restrict__ ids, const float* __restrict__ embW,
                        float* __restrict__ X){
  int n = blockIdx.x;
  int t = threadIdx.x;
  const float4* s = (const float4*)(embW + (size_t)ids[n]*NH);
  float4* d = (float4*)(X + (size_t)n*NH);
  d[t] = s[t];
}

// ---------------- C[4096][Nd] = A[4096][1024] * B[Nd][1024]^T + (bi+bh) ----------------
__global__ __launch_bounds__(256) void k_gemm_nt(
    const float* __restrict__ A, const float* __restrict__ B,
    const float* __restrict__ bi, const float* __restrict__ bh,
    float* __restrict__ C, int Nd)
{
  __shared__ float As[32][68];
  __shared__ float Bs[32][68];
  int m0 = blockIdx.x*64, n0 = blockIdx.y*64;
  int t = threadIdx.x;
  int tm = (t&15)*4, tn = (t>>4)*4;
  int lr = t>>3, lk = (t&7)*4;
  float acc[4][4] = {{0.f}};
  for (int k0=0;k0<NH;k0+=32){
    float4 a0 = *(const float4*)(A + (size_t)(m0+lr)*NH + k0+lk);
    float4 a1 = *(const float4*)(A + (size_t)(m0+lr+32)*NH + k0+lk);
    float4 b0 = *(const float4*)(B + (size_t)(n0+lr)*NH + k0+lk);
    float4 b1 = *(const float4*)(B + (size_t)(n0+lr+32)*NH + k0+lk);
    __syncthreads();
    As[lk+0][lr]=a0.x; As[lk+1][lr]=a0.y; As[lk+2][lr]=a0.z; As[lk+3][lr]=a0.w;
    As[lk+0][lr+32]=a1.x; As[lk+1][lr+32]=a1.y; As[lk+2][lr+32]=a1.z; As[lk+3][lr+32]=a1.w;
    Bs[lk+0][lr]=b0.x; Bs[lk+1][lr]=b0.y; Bs[lk+2][lr]=b0.z; Bs[lk+3][lr]=b0.w;
    Bs[lk+0][lr+32]=b1.x; Bs[lk+1][lr+32]=b1.y; Bs[lk+2][lr+32]=b1.z; Bs[lk+3][lr+32]=b1.w;
    __syncthreads();
    #pragma unroll 8
    for (int kk=0;kk<32;kk++){
      float4 av = *(const float4*)&As[kk][tm];
      float4 bv = *(const float4*)&Bs[kk][tn];
      acc[0][0] += av.x*bv.x; acc[0][1] += av.x*bv.y; acc[0][2] += av.x*bv.z; acc[0][3] += av.x*bv.w;
      acc[1][0] += av.y*bv.x; acc[1][1] += av.y*bv.y; acc[1][2] += av.y*bv.z; acc[1][3] += av.y*bv.w;
      acc[2][0] += av.z*bv.x; acc[2][1] += av.z*bv.y; acc[2][2] += av.z*bv.z; acc[2][3] += av.z*bv.w;
      acc[3][0] += av.w*bv.x; acc[3][1] += av.w*bv.y; acc[3][2] += av.w*bv.z; acc[3][3] += av.w*bv.w;
    }
  }
  #pragma unroll
  for (int i=0;i<4;i++){
    int m = m0+tm+i;
    float bias = bi[m]+bh[m];
    float4 o = make_float4(acc[i][0]+bias, acc[i][1]+bias, acc[i][2]+bias, acc[i][3]+bias);
    *(float4*)(C + (size_t)m*Nd + n0+tn) = o;
  }
}

// ---------------- persistent LSTM recurrence (plain launch + manual grid barrier) ----------------
// 256 blocks; block jj owns hidden cols [jj*4, jj*4+4) -> 16 gate rows, W in LDS.
// Wave kq stages its 32-col slice of each 128-col chunk via global_load_lds
// (wave-private dest, no barriers in pipeline), double-buffered, counted vmcnt.
// Thread = 4 rows x 4 batches. red aliased into hs buf0 -> LDS 137,728 B.

#define WAITVM(N) asm volatile("s_waitcnt vmcnt(" #N ")" ::: "memory")
#define HS(bf,kq,row,col) hsraw[((bf)<<13) + ((kq)<<11) + ((row)<<5) + (col)]

#define ISSUE_CHUNK(c, bf) { \
  _Pragma("unroll") \
  for (int q=0;q<8;q++){ \
    int row_ = q*8 + (lane>>3); \
    int scol_ = ((lane&7)<<2) ^ (((row_>>2)&7)<<2); \
    gl2lds16(hcur + row_*NH + (c)*128 + kq*32 + scol_, &HS(bf,kq,q*8,0)); \
  } }

#define COMPUTE_CHUNK(c, bf) { \
  const int kbase_ = (c)*128 + kq*32; \
  _Pragma("unroll") \
  for (int kk=0; kk<32; kk+=4){ \
    float4 w0 = *(const float4*)&wlds[rg4+0][kbase_+kk]; \
    float4 w1 = *(const float4*)&wlds[rg4+1][kbase_+kk]; \
    float4 w2 = *(const float4*)&wlds[rg4+2][kbase_+kk]; \
    float4 w3 = *(const float4*)&wlds[rg4+3][kbase_+kk]; \
    int xc_ = kk ^ swz; \
    float4 x0 = *(const float4*)&HS(bf,kq,bg4+0,xc_); \
    float4 x1 = *(const float4*)&HS(bf,kq,bg4+1,xc_); \
    float4 x2 = *(const float4*)&HS(bf,kq,bg4+2,xc_); \
    float4 x3 = *(const float4*)&HS(bf,kq,bg4+3,xc_); \
    acc[0][0]+=w0.x*x0.x+w0.y*x0.y+w0.z*x0.z+w0.w*x0.w; \
    acc[0][1]+=w0.x*x1.x+w0.y*x1.y+w0.z*x1.z+w0.w*x1.w; \
    acc[0][2]+=w0.x*x2.x+w0.y*x2.y+w0.z*x2.z+w0.w*x2.w; \
    acc[0][3]+=w0.x*x3.x+w0.y*x3.y+w0.z*x3.z+w0.w*x3.w; \
    acc[1][0]+=w1.x*x0.x+w1.y*x0.y+w1.z*x0.z+w1.w*x0.w; \
    acc[1][1]+=w1.x*x1.x+w1.y*x1.y+w1.z*x1.z+w1.w*x1.w; \
    acc[1][2]+=w1.x*x2.x+w1.y*x2.y+w1.z*x2.z+w1.w*x2.w; \
    acc[1][3]+=w1.x*x3.x+w1.y*x3.y+w1.z*x3.z+w1.w*x3.w; \
    acc[2][0]+=w2.x*x0.x+w2.y*x0.y+w2.z*x0.z+w2.w*x0.w; \
    acc[2][1]+=w2.x*x1.x+w2.y*x1.y+w2.z*x1.z+w2.w*x1.w; \
    acc[2][2]+=w2.x*x2.x+w2.y*x2.y+w2.z*x2.z+w2.w*x2.w; \
    acc[2][3]+=w2.x*x3.x+w2.y*x3.y+w2.z*x3.z+w2.w*x3.w; \
    acc[3][0]+=w3.x*x0.x+w3.y*x0.y+w3.z*x0.z+w3.w*x0.w; \
    acc[3][1]+=w3.x*x1.x+w3.y*x1.y+w3.z*x1.z+w3.w*x1.w; \
    acc[3][2]+=w3.x*x2.x+w3.y*x2.y+w3.z*x2.z+w3.w*x2.w; \
    acc[3][3]+=w3.x*x3.x+w3.y*x3.y+w3.z*x3.z+w3.w*x3.w; \
  } }

__global__ __launch_bounds__(256,1) void k_rec(
    const float* __restrict__ GT, const float* __restrict__ Wh,
    const float* __restrict__ h0, const float* __restrict__ c0,
    float* __restrict__ hb, float* __restrict__ Y,
    float* __restrict__ hN, float* __restrict__ cN,
    unsigned* bar)
{
  __shared__ float wlds[16][1028];     // 65,792 B
  __shared__ float hsraw[16384];       // 65,536 B : hs[2][4][64][32]; red aliases [0..4096)
  __shared__ float glds[64][20];       // 5,120 B
  __shared__ float hvals[64][5];       // 1,280 B
  float* red = hsraw;                  // [4][1024], valid only between the two barriers
  int jj = blockIdx.x, t = threadIdx.x;
  for (int rr=0;rr<16;rr++){
    int grow = (rr>>2)*NH + jj*4 + (rr&3);
    *(float4*)&wlds[rr][t*4] = *(const float4*)(Wh + (size_t)grow*NH + t*4);
  }
  // state-update mapping
  int b = t&63, cc = t>>6;
  int hc = jj*4 + cc;
  // compute mapping
  int kq = t>>6;           // wave = K-quarter
  int lane = t&63;
  int rg4 = ((t>>4)&3)*4;  // 4 gate rows
  int bg4 = (t&15)*4;      // 4 batches
  int swz = ((t&15)&7)<<2; // matches source swizzle ((row>>2)&7)<<2, row=bg4+i
  int r  = t>>4;           // post-reduction gate row (0..15)
  size_t gtrow = ((size_t)(r>>2)*NH + jj*4 + (r&3))*NN;

  float creg = c0[b*NH + hc];
  hb[b*NH + hc] = h0[b*NH + hc];     // state buffer 0
  unsigned ep = 1;
  gbar(bar, ep*256); ep++;

  for (int st=0; st<TSTEPS; st++){
    const float* hcur = hb + (size_t)(st&1)*BB*NH;
    float*       hnxt = hb + (size_t)((st+1)&1)*BB*NH;
    float4 gt4 = *(const float4*)(GT + gtrow + st*64 + bg4);

    float acc[4][4];
    #pragma unroll
    for (int j=0;j<4;j++){
      #pragma unroll
      for (int i=0;i<4;i++) acc[j][i]=0.f;
    }

    ISSUE_CHUNK(0,0);
    ISSUE_CHUNK(1,1); WAITVM(8); COMPUTE_CHUNK(0,0);
    ISSUE_CHUNK(2,0); WAITVM(8); COMPUTE_CHUNK(1,1);
    ISSUE_CHUNK(3,1); WAITVM(8); COMPUTE_CHUNK(2,0);
    ISSUE_CHUNK(4,0); WAITVM(8); COMPUTE_CHUNK(3,1);
    ISSUE_CHUNK(5,1); WAITVM(8); COMPUTE_CHUNK(4,0);
    ISSUE_CHUNK(6,0); WAITVM(8); COMPUTE_CHUNK(5,1);
    ISSUE_CHUNK(7,1); WAITVM(8); COMPUTE_CHUNK(6,0);
                      WAITVM(0); COMPUTE_CHUNK(7,1);

    __syncthreads();   // all waves done reading hs before red-alias write
    // K-quarter reduction across waves (red aliases hs buf0)
    *(float4*)&red[kq*1024 + (rg4+0)*64 + bg4] = make_float4(acc[0][0],acc[0][1],acc[0][2],acc[0][3]);
    *(float4*)&red[kq*1024 + (rg4+1)*64 + bg4] = make_float4(acc[1][0],acc[1][1],acc[1][2],acc[1][3]);
    *(float4*)&red[kq*1024 + (rg4+2)*64 + bg4] = make_float4(acc[2][0],acc[2][1],acc[2][2],acc[2][3]);
    *(float4*)&red[kq*1024 + (rg4+3)*64 + bg4] = make_float4(acc[3][0],acc[3][1],acc[3][2],acc[3][3]);
    __syncthreads();
    float4 s0 = *(const float4*)&red[0*1024 + t*4];
    float4 s1 = *(const float4*)&red[1*1024 + t*4];
    float4 s2 = *(const float4*)&red[2*1024 + t*4];
    float4 s3 = *(const float4*)&red[3*1024 + t*4];
    float4 g4 = make_float4(s0.x+s1.x+s2.x+s3.x + gt4.x,
                            s0.y+s1.y+s2.y+s3.y + gt4.y,
                            s0.z+s1.z+s2.z+s3.z + gt4.z,
                            s0.w+s1.w+s2.w+s3.w + gt4.w);
    glds[bg4+0][r] = g4.x;
    glds[bg4+1][r] = g4.y;
    glds[bg4+2][r] = g4.z;
    glds[bg4+3][r] = g4.w;
    __syncthreads();
    float gi = glds[b][0*4+cc];
    float gf = glds[b][1*4+cc];
    float gg = glds[b][2*4+cc];
    float go = glds[b][3*4+cc];
    float cnew = sigmf(gf)*creg + sigmf(gi)*tanhf(gg);
    creg = cnew;
    float hv = sigmf(go)*tanhf(cnew);
    hvals[b][cc] = hv;
    if (st == TSTEPS-1){ hN[b*NH+hc] = hv; cN[b*NH+hc] = creg; }
    __syncthreads();
    {
      int sb = t>>2, sc = t&3;
      float v = hvals[sb][sc];
      hnxt[sb*NH + jj*4 + sc] = v;
      Y[(size_t)(st*BB+sb)*NH + jj*4 + sc] = v;
    }
    gbar(bar, ep*256); ep++;
  }
}

// ---------------- top logits ----------------
__global__ __launch_bounds__(256) void k_gemm_top(
    const float* __restrict__ X, const float* __restrict__ W,
    const float* __restrict__ bias, float* __restrict__ C)
{
  __shared__ float Xs[32][68];
  __shared__ float Ws[32][36];
  int n0 = blockIdx.x*64, c0 = blockIdx.y*32;
  int t = threadIdx.x;
  int tm = (t&15)*4;
  int tn = (t>>4)*2;
  int lr = t>>3, lk = (t&7)*4;
  float acc[4][2] = {{0.f}};
  for (int k0=0;k0<NH;k0+=32){
    float4 x0 = *(const float4*)(X + (size_t)(n0+lr)*NH + k0+lk);
    float4 x1 = *(const float4*)(X + (size_t)(n0+lr+32)*NH + k0+lk);
    float4 wv = *(const float4*)(W + (size_t)(k0 + (t>>3))*NCLS + c0 + (t&7)*4);
    __syncthreads();
    Xs[lk+0][lr]=x0.x; Xs[lk+1][lr]=x0.y; Xs[lk+2][lr]=x0.z; Xs[lk+3][lr]=x0.w;
    Xs[lk+0][lr+32]=x1.x; Xs[lk+1][lr+32]=x1.y; Xs[lk+2][lr+32]=x1.z; Xs[lk+3][lr+32]=x1.w;
    *(float4*)&Ws[t>>3][(t&7)*4] = wv;
    __syncthreads();
    #pragma unroll 8
    for (int kk=0;kk<32;kk++){
      float4 av = *(const float4*)&Xs[kk][tm];
      float2 bv = *(const float2*)&Ws[kk][tn];
      acc[0][0] += av.x*bv.x; acc[0][1] += av.x*bv.y;
      acc[1][0] += av.y*bv.x; acc[1][1] += av.y*bv.y;
      acc[2][0] += av.z*bv.x; acc[2][1] += av.z*bv.y;
      acc[3][0] += av.w*bv.x; acc[3][1] += av.w*bv.y;
    }
  }
  float bz0 = bias[c0+tn], bz1 = bias[c0+tn+1];
  #pragma unroll
  for (int i=0;i<4;i++){
    float2 o = make_float2(acc[i][0]+bz0, acc[i][1]+bz1);
    *(float2*)(C + (size_t)(n0+tm+i)*NCLS + c0+tn) = o;
  }
}

// ---------------- per-row top softmax pick ----------------
__global__ void k_top_pick(const float* __restrict__ TL, const int* __restrict__ tg,
                           float* __restrict__ ptop){
  int n = blockIdx.x*4 + (threadIdx.x>>6);
  int lane = threadIdx.x&63;
  const float* row = TL + (size_t)n*NCLS;
  float v[4]; float m = -1e30f;
  #pragma unroll
  for (int q=0;q<4;q++){ int c = lane + q*64; v[q] = (c<NCLS)? row[c] : -1e30f; m = fmaxf(m, v[q]); }
  for (int o=32;o;o>>=1) m = fmaxf(m, __shfl_xor(m,o));
  float s = 0.f;
  #pragma unroll
  for (int q=0;q<4;q++){ int c = lane + q*64; if (c<NCLS) s += expf(v[q]-m); }
  for (int o=32;o;o>>=1) s += __shfl_xor(s,o);
  if (lane==0){ int pt = tg[n]/NPC; ptop[n] = expf(row[pt]-m)/s; }
}

// ---------------- class bucketing ----------------
__global__ void k_zero(int* cnt, int* cur){ int t=threadIdx.x; if(t<NCLS){cnt[t]=0; cur[t]=0;} }
__global__ void k_hist(const int* __restrict__ tg, int* cnt){
  int n = blockIdx.x*256+threadIdx.x;
  if (n<NN) atomicAdd(&cnt[tg[n]/NPC],1);
}
__global__ void k_scan(const int* __restrict__ cnt, int* __restrict__ off){
  if (threadIdx.x==0 && blockIdx.x==0){ int a=0; for(int c=0;c<NCLS;c++){ off[c]=a; a+=cnt[c]; } off[NCLS]=a; }
}
__global__ void k_scatter(const int* __restrict__ tg, const int* __restrict__ off,
                          int* cur, int* __restrict__ perm){
  int n = blockIdx.x*256+threadIdx.x;
  if (n<NN){ int c = tg[n]/NPC; int p = atomicAdd(&cur[c],1); perm[off[c]+p] = n; }
}

// ---------------- per-class bottom GEMM + softmax pick + final product ----------------
__global__ __launch_bounds__(256) void k_bot(
    const float* __restrict__ X, const float* __restrict__ botW, const float* __restrict__ botb,
    const int* __restrict__ tg, const int* __restrict__ off, const int* __restrict__ perm,
    const float* __restrict__ ptop, float* __restrict__ outP)
{
  int cls = blockIdx.x;
  int s = off[cls], e = off[cls+1];
  if (s>=e) return;
  __shared__ float xs[16][NH];
  __shared__ float lg[16][228];
  int t = threadIdx.x;
  const float* Wc = botW + (size_t)cls*NH*NPC;
  for (int base=s; base<e; base+=16){
    int nr = min(16, e-base);
    __syncthreads();
    for (int r=0;r<nr;r++){
      int n = perm[base+r];
      *(float4*)&xs[r][t*4] = *(const float4*)(X + (size_t)n*NH + t*4);
    }
    __syncthreads();
    if (t < NPC){
      float acc[16];
      #pragma unroll
      for (int r=0;r<16;r++) acc[r]=0.f;
      for (int k=0;k<NH;k+=2){
        float w0 = Wc[(size_t)k*NPC + t];
        float w1 = Wc[(size_t)(k+1)*NPC + t];
        #pragma unroll
        for (int r=0;r<16;r++){
          float2 x2 = *(const float2*)&xs[r][k];
          acc[r] += x2.x*w0 + x2.y*w1;
        }
      }
      float bb = botb[(size_t)cls*NPC + t];
      for (int r=0;r<nr;r++) lg[r][t] = acc[r] + bb;
    }
    __syncthreads();
    int wv = t>>6, lane = t&63;
    for (int r=wv; r<nr; r+=4){
      float v[4]; float m=-1e30f;
      #pragma unroll
      for (int q=0;q<4;q++){ int c = lane+q*64; v[q] = (c<NPC)? lg[r][c] : -1e30f; m=fmaxf(m,v[q]); }
      for (int o=32;o;o>>=1) m=fmaxf(m,__shfl_xor(m,o));
      float ss=0.f;
      #pragma unroll
      for (int q=0;q<4;q++){ int c = lane+q*64; if (c<NPC) ss += expf(v[q]-m); }
      for (int o=32;o;o>>=1) ss += __shfl_xor(ss,o);
      if (lane==0){
        int n = perm[base+r]; int pb = tg[n]%NPC;
        outP[n] = ptop[n]*expf(lg[r][pb]-m)/ss;
      }
    }
  }
}

extern "C" void kernel_launch(void* const* d_in, const int* in_sizes, int n_in,
                              void* d_out, int out_size, void* d_ws, size_t ws_size,
                              hipStream_t stream)
{
  const int*   ids  = (const int*)d_in[0];
  const int*   tg   = (const int*)d_in[1];
  const float* h0   = (const float*)d_in[2];
  const float* c0   = (const float*)d_in[3];
  const float* embW = (const float*)d_in[4];
  const float* Wih  = (const float*)d_in[5];
  const float* Whh  = (const float*)d_in[6];
  const float* bih  = (const float*)d_in[7];
  const float* bhh  = (const float*)d_in[8];
  const float* topW = (const float*)d_in[9];
  const float* topb = (const float*)d_in[10];
  const float* botW = (const float*)d_in[11];
  const float* botb = (const float*)d_in[12];
  float* out = (float*)d_out;

  float* X  = (float*)d_ws;                    // [NN][NH]
  float* Yb = X  + (size_t)NN*NH;              // [NN][NH]
  float* GT = Yb + (size_t)NN*NH;              // [G4][NN]
  float* hb = GT + (size_t)G4*NN;              // [2][BB][NH]
  float* TL = hb + 2*(size_t)BB*NH;            // [NN][NCLS]
  float* pt = TL + (size_t)NN*NCLS;            // [NN]
  int* cnt  = (int*)(pt + NN);
  int* off  = cnt + NCLS;
  int* cur  = off + NCLS + 1;
  int* perm = cur + NCLS;
  unsigned* bar = (unsigned*)(perm + NN);

  k_embed<<<NN,256,0,stream>>>(ids, embW, X);

  for (int l=0; l<2; l++){
    const float* A   = Wih + (size_t)l*G4*NH;
    const float* Wl  = Whh + (size_t)l*G4*NH;
    const float* bi  = bih + (size_t)l*G4;
    const float* bh  = bhh + (size_t)l*G4;
    const float* Bx  = (l==0)? X : Yb;
    float*       Yo  = (l==0)? Yb : X;
    k_gemm_nt<<<dim3(64,128),256,0,stream>>>(A, Bx, bi, bh, GT, NN);
    const float* h0l = h0 + (size_t)l*BB*NH;
    const float* c0l = c0 + (size_t)l*BB*NH;
    float* hNl = out + NN + (size_t)l*BB*NH;
    float* cNl = out + NN + 2*(size_t)BB*NH + (size_t)l*BB*NH;
    hipMemsetAsync(bar, 0, sizeof(unsigned), stream);
    k_rec<<<256,256,0,stream>>>(GT, Wl, h0l, c0l, hb, Yo, hNl, cNl, bar);
  }

  // X now holds the layer-1 output sequence [NN][NH]
  k_gemm_top<<<dim3(128,7),256,0,stream>>>(X, topW, topb, TL);
  k_top_pick<<<NN/4,256,0,stream>>>(TL, tg, pt);
  k_zero<<<1,256,0,stream>>>(cnt, cur);
  k_hist<<<NN/256,256,0,stream>>>(tg, cnt);
  k_scan<<<1,1,0,stream>>>(cnt, off);
  k_scatter<<<NN/256,256,0,stream>>>(tg, off, cur, perm);
  k_bot<<<NCLS,256,0,stream>>>(X, botW, botb, tg, off, perm, pt, out);
}

// Round 7
// 18001.953 us; speedup vs baseline: 1.1744x; 1.1664x over previous
//
#include <hip/hip_runtime.h>
#include <math.h>

#define NTOK 50257
#define NPC  225
#define NCLS 224
#define NH   1024
#define G4   4096
#define TSTEPS 128
#define BB   64
#define NN   8192

__device__ __forceinline__ float sigmf(float x){ return 1.0f/(1.0f+expf(-x)); }

__device__ __forceinline__ void gl2lds16(const float* g, float* l){
  __builtin_amdgcn_global_load_lds(
      (const __attribute__((address_space(1))) unsigned int*)(g),
      (__attribute__((address_space(3))) unsigned int*)(l), 16, 0, 0);
}

// flag-array grid barrier: block j store-releases flags[j]=ep (distinct addresses,
// no RMW serialization); thread t polls flags[t] until >= ep. Grid co-resident by
// construction (1 block/CU x 256 blocks).
__device__ __forceinline__ void gbar(unsigned* flags, unsigned ep){
  __threadfence();                 // release my h/Y stores (wbl2)
  __syncthreads();
  if (threadIdx.x==0)
    __hip_atomic_store(&flags[blockIdx.x], ep, __ATOMIC_RELAXED, __HIP_MEMORY_SCOPE_AGENT);
  while (__hip_atomic_load(&flags[threadIdx.x], __ATOMIC_RELAXED, __HIP_MEMORY_SCOPE_AGENT) < ep)
    __builtin_amdgcn_s_sleep(2);
  __syncthreads();
  __threadfence();                 // acquire: invalidate stale lines
}

// ---------------- embedding gather ----------------
__global__ void k_embed(const int* __restrict__ ids, const float* __restrict__ embW,
                        float* __restrict__ X){
  int n = blockIdx.x;
  int t = threadIdx.x;
  const float4* s = (const float4*)(embW + (size_t)ids[n]*NH);
  float4* d = (float4*)(X + (size_t)n*NH);
  d[t] = s[t];
}

// ---------------- C[4096][Nd] = A[4096][1024] * B[Nd][1024]^T + (bi+bh) ----------------
__global__ __launch_bounds__(256) void k_gemm_nt(
    const float* __restrict__ A, const float* __restrict__ B,
    const float* __restrict__ bi, const float* __restrict__ bh,
    float* __restrict__ C, int Nd)
{
  __shared__ float As[32][68];
  __shared__ float Bs[32][68];
  int m0 = blockIdx.x*64, n0 = blockIdx.y*64;
  int t = threadIdx.x;
  int tm = (t&15)*4, tn = (t>>4)*4;
  int lr = t>>3, lk = (t&7)*4;
  float acc[4][4] = {{0.f}};
  for (int k0=0;k0<NH;k0+=32){
    float4 a0 = *(const float4*)(A + (size_t)(m0+lr)*NH + k0+lk);
    float4 a1 = *(const float4*)(A + (size_t)(m0+lr+32)*NH + k0+lk);
    float4 b0 = *(const float4*)(B + (size_t)(n0+lr)*NH + k0+lk);
    float4 b1 = *(const float4*)(B + (size_t)(n0+lr+32)*NH + k0+lk);
    __syncthreads();
    As[lk+0][lr]=a0.x; As[lk+1][lr]=a0.y; As[lk+2][lr]=a0.z; As[lk+3][lr]=a0.w;
    As[lk+0][lr+32]=a1.x; As[lk+1][lr+32]=a1.y; As[lk+2][lr+32]=a1.z; As[lk+3][lr+32]=a1.w;
    Bs[lk+0][lr]=b0.x; Bs[lk+1][lr]=b0.y; Bs[lk+2][lr]=b0.z; Bs[lk+3][lr]=b0.w;
    Bs[lk+0][lr+32]=b1.x; Bs[lk+1][lr+32]=b1.y; Bs[lk+2][lr+32]=b1.z; Bs[lk+3][lr+32]=b1.w;
    __syncthreads();
    #pragma unroll 8
    for (int kk=0;kk<32;kk++){
      float4 av = *(const float4*)&As[kk][tm];
      float4 bv = *(const float4*)&Bs[kk][tn];
      acc[0][0] += av.x*bv.x; acc[0][1] += av.x*bv.y; acc[0][2] += av.x*bv.z; acc[0][3] += av.x*bv.w;
      acc[1][0] += av.y*bv.x; acc[1][1] += av.y*bv.y; acc[1][2] += av.y*bv.z; acc[1][3] += av.y*bv.w;
      acc[2][0] += av.z*bv.x; acc[2][1] += av.z*bv.y; acc[2][2] += av.z*bv.z; acc[2][3] += av.z*bv.w;
      acc[3][0] += av.w*bv.x; acc[3][1] += av.w*bv.y; acc[3][2] += av.w*bv.z; acc[3][3] += av.w*bv.w;
    }
  }
  #pragma unroll
  for (int i=0;i<4;i++){
    int m = m0+tm+i;
    float bias = bi[m]+bh[m];
    float4 o = make_float4(acc[i][0]+bias, acc[i][1]+bias, acc[i][2]+bias, acc[i][3]+bias);
    *(float4*)(C + (size_t)m*Nd + n0+tn) = o;
  }
}

// ---------------- persistent LSTM recurrence (flag-array grid barrier) ----------------
// 256 blocks; block jj owns hidden cols [jj*4, jj*4+4) -> 16 gate rows, W in LDS.
// Wave kq stages its 32-col slice of each 128-col chunk via global_load_lds
// (wave-private dest, no barriers in pipeline), double-buffered, counted vmcnt.
// Thread = 4 rows x 4 batches. red aliased into hs buf0 -> LDS 137,728 B.

#define WAITVM(N) asm volatile("s_waitcnt vmcnt(" #N ")" ::: "memory")
#define HS(bf,kq,row,col) hsraw[((bf)<<13) + ((kq)<<11) + ((row)<<5) + (col)]

#define ISSUE_CHUNK(c, bf) { \
  _Pragma("unroll") \
  for (int q=0;q<8;q++){ \
    int row_ = q*8 + (lane>>3); \
    int scol_ = ((lane&7)<<2) ^ (((row_>>2)&7)<<2); \
    gl2lds16(hcur + row_*NH + (c)*128 + kq*32 + scol_, &HS(bf,kq,q*8,0)); \
  } }

#define COMPUTE_CHUNK(c, bf) { \
  const int kbase_ = (c)*128 + kq*32; \
  _Pragma("unroll") \
  for (int kk=0; kk<32; kk+=4){ \
    float4 w0 = *(const float4*)&wlds[rg4+0][kbase_+kk]; \
    float4 w1 = *(const float4*)&wlds[rg4+1][kbase_+kk]; \
    float4 w2 = *(const float4*)&wlds[rg4+2][kbase_+kk]; \
    float4 w3 = *(const float4*)&wlds[rg4+3][kbase_+kk]; \
    int xc_ = kk ^ swz; \
    float4 x0 = *(const float4*)&HS(bf,kq,bg4+0,xc_); \
    float4 x1 = *(const float4*)&HS(bf,kq,bg4+1,xc_); \
    float4 x2 = *(const float4*)&HS(bf,kq,bg4+2,xc_); \
    float4 x3 = *(const float4*)&HS(bf,kq,bg4+3,xc_); \
    acc[0][0]+=w0.x*x0.x+w0.y*x0.y+w0.z*x0.z+w0.w*x0.w; \
    acc[0][1]+=w0.x*x1.x+w0.y*x1.y+w0.z*x1.z+w0.w*x1.w; \
    acc[0][2]+=w0.x*x2.x+w0.y*x2.y+w0.z*x2.z+w0.w*x2.w; \
    acc[0][3]+=w0.x*x3.x+w0.y*x3.y+w0.z*x3.z+w0.w*x3.w; \
    acc[1][0]+=w1.x*x0.x+w1.y*x0.y+w1.z*x0.z+w1.w*x0.w; \
    acc[1][1]+=w1.x*x1.x+w1.y*x1.y+w1.z*x1.z+w1.w*x1.w; \
    acc[1][2]+=w1.x*x2.x+w1.y*x2.y+w1.z*x2.z+w1.w*x2.w; \
    acc[1][3]+=w1.x*x3.x+w1.y*x3.y+w1.z*x3.z+w1.w*x3.w; \
    acc[2][0]+=w2.x*x0.x+w2.y*x0.y+w2.z*x0.z+w2.w*x0.w; \
    acc[2][1]+=w2.x*x1.x+w2.y*x1.y+w2.z*x1.z+w2.w*x1.w; \
    acc[2][2]+=w2.x*x2.x+w2.y*x2.y+w2.z*x2.z+w2.w*x2.w; \
    acc[2][3]+=w2.x*x3.x+w2.y*x3.y+w2.z*x3.z+w2.w*x3.w; \
    acc[3][0]+=w3.x*x0.x+w3.y*x0.y+w3.z*x0.z+w3.w*x0.w; \
    acc[3][1]+=w3.x*x1.x+w3.y*x1.y+w3.z*x1.z+w3.w*x1.w; \
    acc[3][2]+=w3.x*x2.x+w3.y*x2.y+w3.z*x2.z+w3.w*x2.w; \
    acc[3][3]+=w3.x*x3.x+w3.y*x3.y+w3.z*x3.z+w3.w*x3.w; \
  } }

__global__ __launch_bounds__(256,1) void k_rec(
    const float* __restrict__ GT, const float* __restrict__ Wh,
    const float* __restrict__ h0, const float* __restrict__ c0,
    float* __restrict__ hb, float* __restrict__ Y,
    float* __restrict__ hN, float* __restrict__ cN,
    unsigned* flags)
{
  __shared__ float wlds[16][1028];     // 65,792 B
  __shared__ float hsraw[16384];       // 65,536 B : hs[2][4][64][32]; red aliases [0..4096)
  __shared__ float glds[64][20];       // 5,120 B
  __shared__ float hvals[64][5];       // 1,280 B
  float* red = hsraw;                  // [4][1024], valid only between the two barriers
  int jj = blockIdx.x, t = threadIdx.x;
  for (int rr=0;rr<16;rr++){
    int grow = (rr>>2)*NH + jj*4 + (rr&3);
    *(float4*)&wlds[rr][t*4] = *(const float4*)(Wh + (size_t)grow*NH + t*4);
  }
  // state-update mapping
  int b = t&63, cc = t>>6;
  int hc = jj*4 + cc;
  // compute mapping
  int kq = t>>6;           // wave = K-quarter
  int lane = t&63;
  int rg4 = ((t>>4)&3)*4;  // 4 gate rows
  int bg4 = (t&15)*4;      // 4 batches
  int swz = ((t&15)&7)<<2; // matches source swizzle ((row>>2)&7)<<2, row=bg4+i
  int r  = t>>4;           // post-reduction gate row (0..15)
  size_t gtrow = ((size_t)(r>>2)*NH + jj*4 + (r&3))*NN;

  float creg = c0[b*NH + hc];
  hb[b*NH + hc] = h0[b*NH + hc];     // state buffer 0
  unsigned ep = 1;
  gbar(flags, ep); ep++;

  for (int st=0; st<TSTEPS; st++){
    const float* hcur = hb + (size_t)(st&1)*BB*NH;
    float*       hnxt = hb + (size_t)((st+1)&1)*BB*NH;
    float4 gt4 = *(const float4*)(GT + gtrow + st*64 + bg4);

    float acc[4][4];
    #pragma unroll
    for (int j=0;j<4;j++){
      #pragma unroll
      for (int i=0;i<4;i++) acc[j][i]=0.f;
    }

    ISSUE_CHUNK(0,0);
    ISSUE_CHUNK(1,1); WAITVM(8); COMPUTE_CHUNK(0,0);
    ISSUE_CHUNK(2,0); WAITVM(8); COMPUTE_CHUNK(1,1);
    ISSUE_CHUNK(3,1); WAITVM(8); COMPUTE_CHUNK(2,0);
    ISSUE_CHUNK(4,0); WAITVM(8); COMPUTE_CHUNK(3,1);
    ISSUE_CHUNK(5,1); WAITVM(8); COMPUTE_CHUNK(4,0);
    ISSUE_CHUNK(6,0); WAITVM(8); COMPUTE_CHUNK(5,1);
    ISSUE_CHUNK(7,1); WAITVM(8); COMPUTE_CHUNK(6,0);
                      WAITVM(0); COMPUTE_CHUNK(7,1);

    __syncthreads();   // all waves done reading hs before red-alias write
    // K-quarter reduction across waves (red aliases hs buf0)
    *(float4*)&red[kq*1024 + (rg4+0)*64 + bg4] = make_float4(acc[0][0],acc[0][1],acc[0][2],acc[0][3]);
    *(float4*)&red[kq*1024 + (rg4+1)*64 + bg4] = make_float4(acc[1][0],acc[1][1],acc[1][2],acc[1][3]);
    *(float4*)&red[kq*1024 + (rg4+2)*64 + bg4] = make_float4(acc[2][0],acc[2][1],acc[2][2],acc[2][3]);
    *(float4*)&red[kq*1024 + (rg4+3)*64 + bg4] = make_float4(acc[3][0],acc[3][1],acc[3][2],acc[3][3]);
    __syncthreads();
    float4 s0 = *(const float4*)&red[0*1024 + t*4];
    float4 s1 = *(const float4*)&red[1*1024 + t*4];
    float4 s2 = *(const float4*)&red[2*1024 + t*4];
    float4 s3 = *(const float4*)&red[3*1024 + t*4];
    float4 g4 = make_float4(s0.x+s1.x+s2.x+s3.x + gt4.x,
                            s0.y+s1.y+s2.y+s3.y + gt4.y,
                            s0.z+s1.z+s2.z+s3.z + gt4.z,
                            s0.w+s1.w+s2.w+s3.w + gt4.w);
    glds[bg4+0][r] = g4.x;
    glds[bg4+1][r] = g4.y;
    glds[bg4+2][r] = g4.z;
    glds[bg4+3][r] = g4.w;
    __syncthreads();
    float gi = glds[b][0*4+cc];
    float gf = glds[b][1*4+cc];
    float gg = glds[b][2*4+cc];
    float go = glds[b][3*4+cc];
    float cnew = sigmf(gf)*creg + sigmf(gi)*tanhf(gg);
    creg = cnew;
    float hv = sigmf(go)*tanhf(cnew);
    hvals[b][cc] = hv;
    if (st == TSTEPS-1){ hN[b*NH+hc] = hv; cN[b*NH+hc] = creg; }
    __syncthreads();
    {
      int sb = t>>2, sc = t&3;
      float v = hvals[sb][sc];
      hnxt[sb*NH + jj*4 + sc] = v;
      Y[(size_t)(st*BB+sb)*NH + jj*4 + sc] = v;
    }
    gbar(flags, ep); ep++;
  }
}

// ---------------- top logits ----------------
__global__ __launch_bounds__(256) void k_gemm_top(
    const float* __restrict__ X, const float* __restrict__ W,
    const float* __restrict__ bias, float* __restrict__ C)
{
  __shared__ float Xs[32][68];
  __shared__ float Ws[32][36];
  int n0 = blockIdx.x*64, c0 = blockIdx.y*32;
  int t = threadIdx.x;
  int tm = (t&15)*4;
  int tn = (t>>4)*2;
  int lr = t>>3, lk = (t&7)*4;
  float acc[4][2] = {{0.f}};
  for (int k0=0;k0<NH;k0+=32){
    float4 x0 = *(const float4*)(X + (size_t)(n0+lr)*NH + k0+lk);
    float4 x1 = *(const float4*)(X + (size_t)(n0+lr+32)*NH + k0+lk);
    float4 wv = *(const float4*)(W + (size_t)(k0 + (t>>3))*NCLS + c0 + (t&7)*4);
    __syncthreads();
    Xs[lk+0][lr]=x0.x; Xs[lk+1][lr]=x0.y; Xs[lk+2][lr]=x0.z; Xs[lk+3][lr]=x0.w;
    Xs[lk+0][lr+32]=x1.x; Xs[lk+1][lr+32]=x1.y; Xs[lk+2][lr+32]=x1.z; Xs[lk+3][lr+32]=x1.w;
    *(float4*)&Ws[t>>3][(t&7)*4] = wv;
    __syncthreads();
    #pragma unroll 8
    for (int kk=0;kk<32;kk++){
      float4 av = *(const float4*)&Xs[kk][tm];
      float2 bv = *(const float2*)&Ws[kk][tn];
      acc[0][0] += av.x*bv.x; acc[0][1] += av.x*bv.y;
      acc[1][0] += av.y*bv.x; acc[1][1] += av.y*bv.y;
      acc[2][0] += av.z*bv.x; acc[2][1] += av.z*bv.y;
      acc[3][0] += av.w*bv.x; acc[3][1] += av.w*bv.y;
    }
  }
  float bz0 = bias[c0+tn], bz1 = bias[c0+tn+1];
  #pragma unroll
  for (int i=0;i<4;i++){
    float2 o = make_float2(acc[i][0]+bz0, acc[i][1]+bz1);
    *(float2*)(C + (size_t)(n0+tm+i)*NCLS + c0+tn) = o;
  }
}

// ---------------- per-row top softmax pick ----------------
__global__ void k_top_pick(const float* __restrict__ TL, const int* __restrict__ tg,
                           float* __restrict__ ptop){
  int n = blockIdx.x*4 + (threadIdx.x>>6);
  int lane = threadIdx.x&63;
  const float* row = TL + (size_t)n*NCLS;
  float v[4]; float m = -1e30f;
  #pragma unroll
  for (int q=0;q<4;q++){ int c = lane + q*64; v[q] = (c<NCLS)? row[c] : -1e30f; m = fmaxf(m, v[q]); }
  for (int o=32;o;o>>=1) m = fmaxf(m, __shfl_xor(m,o));
  float s = 0.f;
  #pragma unroll
  for (int q=0;q<4;q++){ int c = lane + q*64; if (c<NCLS) s += expf(v[q]-m); }
  for (int o=32;o;o>>=1) s += __shfl_xor(s,o);
  if (lane==0){ int pt = tg[n]/NPC; ptop[n] = expf(row[pt]-m)/s; }
}

// ---------------- class bucketing ----------------
__global__ void k_zero(int* cnt, int* cur){ int t=threadIdx.x; if(t<NCLS){cnt[t]=0; cur[t]=0;} }
__global__ void k_hist(const int* __restrict__ tg, int* cnt){
  int n = blockIdx.x*256+threadIdx.x;
  if (n<NN) atomicAdd(&cnt[tg[n]/NPC],1);
}
__global__ void k_scan(const int* __restrict__ cnt, int* __restrict__ off){
  if (threadIdx.x==0 && blockIdx.x==0){ int a=0; for(int c=0;c<NCLS;c++){ off[c]=a; a+=cnt[c]; } off[NCLS]=a; }
}
__global__ void k_scatter(const int* __restrict__ tg, const int* __restrict__ off,
                          int* cur, int* __restrict__ perm){
  int n = blockIdx.x*256+threadIdx.x;
  if (n<NN){ int c = tg[n]/NPC; int p = atomicAdd(&cur[c],1); perm[off[c]+p] = n; }
}

// ---------------- per-class bottom GEMM + softmax pick + final product ----------------
__global__ __launch_bounds__(256) void k_bot(
    const float* __restrict__ X, const float* __restrict__ botW, const float* __restrict__ botb,
    const int* __restrict__ tg, const int* __restrict__ off, const int* __restrict__ perm,
    const float* __restrict__ ptop, float* __restrict__ outP)
{
  int cls = blockIdx.x;
  int s = off[cls], e = off[cls+1];
  if (s>=e) return;
  __shared__ float xs[16][NH];
  __shared__ float lg[16][228];
  int t = threadIdx.x;
  const float* Wc = botW + (size_t)cls*NH*NPC;
  for (int base=s; base<e; base+=16){
    int nr = min(16, e-base);
    __syncthreads();
    for (int r=0;r<nr;r++){
      int n = perm[base+r];
      *(float4*)&xs[r][t*4] = *(const float4*)(X + (size_t)n*NH + t*4);
    }
    __syncthreads();
    if (t < NPC){
      float acc[16];
      #pragma unroll
      for (int r=0;r<16;r++) acc[r]=0.f;
      for (int k=0;k<NH;k+=2){
        float w0 = Wc[(size_t)k*NPC + t];
        float w1 = Wc[(size_t)(k+1)*NPC + t];
        #pragma unroll
        for (int r=0;r<16;r++){
          float2 x2 = *(const float2*)&xs[r][k];
          acc[r] += x2.x*w0 + x2.y*w1;
        }
      }
      float bb = botb[(size_t)cls*NPC + t];
      for (int r=0;r<nr;r++) lg[r][t] = acc[r] + bb;
    }
    __syncthreads();
    int wv = t>>6, lane = t&63;
    for (int r=wv; r<nr; r+=4){
      float v[4]; float m=-1e30f;
      #pragma unroll
      for (int q=0;q<4;q++){ int c = lane+q*64; v[q] = (c<NPC)? lg[r][c] : -1e30f; m=fmaxf(m,v[q]); }
      for (int o=32;o;o>>=1) m=fmaxf(m,__shfl_xor(m,o));
      float ss=0.f;
      #pragma unroll
      for (int q=0;q<4;q++){ int c = lane+q*64; if (c<NPC) ss += expf(v[q]-m); }
      for (int o=32;o;o>>=1) ss += __shfl_xor(ss,o);
      if (lane==0){
        int n = perm[base+r]; int pb = tg[n]%NPC;
        outP[n] = ptop[n]*expf(lg[r][pb]-m)/ss;
      }
    }
  }
}

extern "C" void kernel_launch(void* const* d_in, const int* in_sizes, int n_in,
                              void* d_out, int out_size, void* d_ws, size_t ws_size,
                              hipStream_t stream)
{
  const int*   ids  = (const int*)d_in[0];
  const int*   tg   = (const int*)d_in[1];
  const float* h0   = (const float*)d_in[2];
  const float* c0   = (const float*)d_in[3];
  const float* embW = (const float*)d_in[4];
  const float* Wih  = (const float*)d_in[5];
  const float* Whh  = (const float*)d_in[6];
  const float* bih  = (const float*)d_in[7];
  const float* bhh  = (const float*)d_in[8];
  const float* topW = (const float*)d_in[9];
  const float* topb = (const float*)d_in[10];
  const float* botW = (const float*)d_in[11];
  const float* botb = (const float*)d_in[12];
  float* out = (float*)d_out;

  float* X  = (float*)d_ws;                    // [NN][NH]
  float* Yb = X  + (size_t)NN*NH;              // [NN][NH]
  float* GT = Yb + (size_t)NN*NH;              // [G4][NN]
  float* hb = GT + (size_t)G4*NN;              // [2][BB][NH]
  float* TL = hb + 2*(size_t)BB*NH;            // [NN][NCLS]
  float* pt = TL + (size_t)NN*NCLS;            // [NN]
  int* cnt  = (int*)(pt + NN);
  int* off  = cnt + NCLS;
  int* cur  = off + NCLS + 1;
  int* perm = cur + NCLS;
  unsigned* flags = (unsigned*)(perm + NN);    // [256]

  k_embed<<<NN,256,0,stream>>>(ids, embW, X);

  for (int l=0; l<2; l++){
    const float* A   = Wih + (size_t)l*G4*NH;
    const float* Wl  = Whh + (size_t)l*G4*NH;
    const float* bi  = bih + (size_t)l*G4;
    const float* bh  = bhh + (size_t)l*G4;
    const float* Bx  = (l==0)? X : Yb;
    float*       Yo  = (l==0)? Yb : X;
    k_gemm_nt<<<dim3(64,128),256,0,stream>>>(A, Bx, bi, bh, GT, NN);
    const float* h0l = h0 + (size_t)l*BB*NH;
    const float* c0l = c0 + (size_t)l*BB*NH;
    float* hNl = out + NN + (size_t)l*BB*NH;
    float* cNl = out + NN + 2*(size_t)BB*NH + (size_t)l*BB*NH;
    hipMemsetAsync(flags, 0, 256*sizeof(unsigned), stream);
    k_rec<<<256,256,0,stream>>>(GT, Wl, h0l, c0l, hb, Yo, hNl, cNl, flags);
  }

  // X now holds the layer-1 output sequence [NN][NH]
  k_gemm_top<<<dim3(128,7),256,0,stream>>>(X, topW, topb, TL);
  k_top_pick<<<NN/4,256,0,stream>>>(TL, tg, pt);
  k_zero<<<1,256,0,stream>>>(cnt, cur);
  k_hist<<<NN/256,256,0,stream>>>(tg, cnt);
  k_scan<<<1,1,0,stream>>>(cnt, off);
  k_scatter<<<NN/256,256,0,stream>>>(tg, off, cur, perm);
  k_bot<<<NCLS,256,0,stream>>>(X, botW, botb, tg, off, perm, pt, out);
}

// Round 9
// 7990.779 us; speedup vs baseline: 2.6456x; 2.2528x over previous
//
#include <hip/hip_runtime.h>
#include <math.h>

#define NTOK 50257
#define NPC  225
#define NCLS 224
#define NH   1024
#define G4   4096
#define TSTEPS 128
#define BB   64
#define NN   8192

__device__ __forceinline__ float sigmf(float x){ return 1.0f/(1.0f+expf(-x)); }

// global->LDS DMA with cache-policy aux (literal via template): 17 = SC0|SC1
// (agent-coherent read, bypasses stale L1/L2 and reads from the coherence point)
template<int AUX>
__device__ __forceinline__ void gl2lds16(const float* g, float* l){
  __builtin_amdgcn_global_load_lds(
      (const __attribute__((address_space(1))) unsigned int*)(g),
      (__attribute__((address_space(3))) unsigned int*)(l), 16, 0, AUX);
}

// flag-array grid barrier WITHOUT cache-wide fences. All shared state (h, flags)
// travels the agent-coherent sc0/sc1 path, so release = drain own VMEM (vmcnt 0);
// no buffer_wbl2 / buffer_inv needed. Grid co-resident: 1 block/CU x 256.
__device__ __forceinline__ void gbar(unsigned* flags, unsigned ep){
  asm volatile("s_waitcnt vmcnt(0) lgkmcnt(0)" ::: "memory");
  __syncthreads();
  if (threadIdx.x==0)
    __hip_atomic_store(&flags[blockIdx.x], ep, __ATOMIC_RELAXED, __HIP_MEMORY_SCOPE_AGENT);
  while (__hip_atomic_load(&flags[threadIdx.x], __ATOMIC_RELAXED, __HIP_MEMORY_SCOPE_AGENT) < ep)
    __builtin_amdgcn_s_sleep(2);
  __syncthreads();
}

// ---------------- embedding gather ----------------
__global__ void k_embed(const int* __restrict__ ids, const float* __restrict__ embW,
                        float* __restrict__ X){
  int n = blockIdx.x;
  int t = threadIdx.x;
  const float4* s = (const float4*)(embW + (size_t)ids[n]*NH);
  float4* d = (float4*)(X + (size_t)n*NH);
  d[t] = s[t];
}

// ---------------- C[4096][Nd] = A[4096][1024] * B[Nd][1024]^T + (bi+bh) ----------------
__global__ __launch_bounds__(256) void k_gemm_nt(
    const float* __restrict__ A, const float* __restrict__ B,
    const float* __restrict__ bi, const float* __restrict__ bh,
    float* __restrict__ C, int Nd)
{
  __shared__ float As[32][68];
  __shared__ float Bs[32][68];
  int m0 = blockIdx.x*64, n0 = blockIdx.y*64;
  int t = threadIdx.x;
  int tm = (t&15)*4, tn = (t>>4)*4;
  int lr = t>>3, lk = (t&7)*4;
  float acc[4][4] = {{0.f}};
  for (int k0=0;k0<NH;k0+=32){
    float4 a0 = *(const float4*)(A + (size_t)(m0+lr)*NH + k0+lk);
    float4 a1 = *(const float4*)(A + (size_t)(m0+lr+32)*NH + k0+lk);
    float4 b0 = *(const float4*)(B + (size_t)(n0+lr)*NH + k0+lk);
    float4 b1 = *(const float4*)(B + (size_t)(n0+lr+32)*NH + k0+lk);
    __syncthreads();
    As[lk+0][lr]=a0.x; As[lk+1][lr]=a0.y; As[lk+2][lr]=a0.z; As[lk+3][lr]=a0.w;
    As[lk+0][lr+32]=a1.x; As[lk+1][lr+32]=a1.y; As[lk+2][lr+32]=a1.z; As[lk+3][lr+32]=a1.w;
    Bs[lk+0][lr]=b0.x; Bs[lk+1][lr]=b0.y; Bs[lk+2][lr]=b0.z; Bs[lk+3][lr]=b0.w;
    Bs[lk+0][lr+32]=b1.x; Bs[lk+1][lr+32]=b1.y; Bs[lk+2][lr+32]=b1.z; Bs[lk+3][lr+32]=b1.w;
    __syncthreads();
    #pragma unroll 8
    for (int kk=0;kk<32;kk++){
      float4 av = *(const float4*)&As[kk][tm];
      float4 bv = *(const float4*)&Bs[kk][tn];
      acc[0][0] += av.x*bv.x; acc[0][1] += av.x*bv.y; acc[0][2] += av.x*bv.z; acc[0][3] += av.x*bv.w;
      acc[1][0] += av.y*bv.x; acc[1][1] += av.y*bv.y; acc[1][2] += av.y*bv.z; acc[1][3] += av.y*bv.w;
      acc[2][0] += av.z*bv.x; acc[2][1] += av.z*bv.y; acc[2][2] += av.z*bv.z; acc[2][3] += av.z*bv.w;
      acc[3][0] += av.w*bv.x; acc[3][1] += av.w*bv.y; acc[3][2] += av.w*bv.z; acc[3][3] += av.w*bv.w;
    }
  }
  #pragma unroll
  for (int i=0;i<4;i++){
    int m = m0+tm+i;
    float bias = bi[m]+bh[m];
    float4 o = make_float4(acc[i][0]+bias, acc[i][1]+bias, acc[i][2]+bias, acc[i][3]+bias);
    *(float4*)(C + (size_t)m*Nd + n0+tn) = o;
  }
}

// ---------------- persistent LSTM recurrence (fence-free, IF$-coherent h exchange) ----------------
// 256 blocks; block jj owns hidden cols [jj*4, jj*4+4) -> 16 gate rows, W in LDS.
// Wave kq stages its 32-col slice of each 128-col chunk via global_load_lds aux=SC0|SC1
// (wave-private dest, no barriers in pipeline), double-buffered, counted vmcnt.
// h stores are agent-scope atomics (sc0 sc1 write-through). LDS 137,728 B.

#define WAITVM(N) asm volatile("s_waitcnt vmcnt(" #N ")" ::: "memory")
#define HS(bf,kq,row,col) hsraw[((bf)<<13) + ((kq)<<11) + ((row)<<5) + (col)]

#define ISSUE_CHUNK(c, bf) { \
  _Pragma("unroll") \
  for (int q=0;q<8;q++){ \
    int row_ = q*8 + (lane>>3); \
    int scol_ = ((lane&7)<<2) ^ (((row_>>2)&7)<<2); \
    gl2lds16<17>(hcur + row_*NH + (c)*128 + kq*32 + scol_, &HS(bf,kq,q*8,0)); \
  } }

#define COMPUTE_CHUNK(c, bf) { \
  const int kbase_ = (c)*128 + kq*32; \
  _Pragma("unroll") \
  for (int kk=0; kk<32; kk+=4){ \
    float4 w0 = *(const float4*)&wlds[rg4+0][kbase_+kk]; \
    float4 w1 = *(const float4*)&wlds[rg4+1][kbase_+kk]; \
    float4 w2 = *(const float4*)&wlds[rg4+2][kbase_+kk]; \
    float4 w3 = *(const float4*)&wlds[rg4+3][kbase_+kk]; \
    int xc_ = kk ^ swz; \
    float4 x0 = *(const float4*)&HS(bf,kq,bg4+0,xc_); \
    float4 x1 = *(const float4*)&HS(bf,kq,bg4+1,xc_); \
    float4 x2 = *(const float4*)&HS(bf,kq,bg4+2,xc_); \
    float4 x3 = *(const float4*)&HS(bf,kq,bg4+3,xc_); \
    acc[0][0]+=w0.x*x0.x+w0.y*x0.y+w0.z*x0.z+w0.w*x0.w; \
    acc[0][1]+=w0.x*x1.x+w0.y*x1.y+w0.z*x1.z+w0.w*x1.w; \
    acc[0][2]+=w0.x*x2.x+w0.y*x2.y+w0.z*x2.z+w0.w*x2.w; \
    acc[0][3]+=w0.x*x3.x+w0.y*x3.y+w0.z*x3.z+w0.w*x3.w; \
    acc[1][0]+=w1.x*x0.x+w1.y*x0.y+w1.z*x0.z+w1.w*x0.w; \
    acc[1][1]+=w1.x*x1.x+w1.y*x1.y+w1.z*x1.z+w1.w*x1.w; \
    acc[1][2]+=w1.x*x2.x+w1.y*x2.y+w1.z*x2.z+w1.w*x2.w; \
    acc[1][3]+=w1.x*x3.x+w1.y*x3.y+w1.z*x3.z+w1.w*x3.w; \
    acc[2][0]+=w2.x*x0.x+w2.y*x0.y+w2.z*x0.z+w2.w*x0.w; \
    acc[2][1]+=w2.x*x1.x+w2.y*x1.y+w2.z*x1.z+w2.w*x1.w; \
    acc[2][2]+=w2.x*x2.x+w2.y*x2.y+w2.z*x2.z+w2.w*x2.w; \
    acc[2][3]+=w2.x*x3.x+w2.y*x3.y+w2.z*x3.z+w2.w*x3.w; \
    acc[3][0]+=w3.x*x0.x+w3.y*x0.y+w3.z*x0.z+w3.w*x0.w; \
    acc[3][1]+=w3.x*x1.x+w3.y*x1.y+w3.z*x1.z+w3.w*x1.w; \
    acc[3][2]+=w3.x*x2.x+w3.y*x2.y+w3.z*x2.z+w3.w*x2.w; \
    acc[3][3]+=w3.x*x3.x+w3.y*x3.y+w3.z*x3.z+w3.w*x3.w; \
  } }

__global__ __launch_bounds__(256,1) void k_rec(
    const float* __restrict__ GT, const float* __restrict__ Wh,
    const float* __restrict__ h0, const float* __restrict__ c0,
    float* __restrict__ hb, float* __restrict__ Y,
    float* __restrict__ hN, float* __restrict__ cN,
    unsigned* flags)
{
  __shared__ float wlds[16][1028];     // 65,792 B
  __shared__ float hsraw[16384];       // 65,536 B : hs[2][4][64][32]; red aliases [0..4096)
  __shared__ float glds[64][20];       // 5,120 B
  __shared__ float hvals[64][5];       // 1,280 B
  float* red = hsraw;                  // [4][1024], valid only between the two barriers
  int jj = blockIdx.x, t = threadIdx.x;
  for (int rr=0;rr<16;rr++){
    int grow = (rr>>2)*NH + jj*4 + (rr&3);
    *(float4*)&wlds[rr][t*4] = *(const float4*)(Wh + (size_t)grow*NH + t*4);
  }
  // state-update mapping
  int b = t&63, cc = t>>6;
  int hc = jj*4 + cc;
  // compute mapping
  int kq = t>>6;           // wave = K-quarter
  int lane = t&63;
  int rg4 = ((t>>4)&3)*4;  // 4 gate rows
  int bg4 = (t&15)*4;      // 4 batches
  int swz = ((t&15)&7)<<2; // matches source swizzle ((row>>2)&7)<<2, row=bg4+i
  int r  = t>>4;           // post-reduction gate row (0..15)
  size_t gtrow = ((size_t)(r>>2)*NH + jj*4 + (r&3))*NN;

  float creg = c0[b*NH + hc];
  __hip_atomic_store(&hb[b*NH + hc], h0[b*NH + hc],
                     __ATOMIC_RELAXED, __HIP_MEMORY_SCOPE_AGENT);  // state buffer 0 via IF$
  unsigned ep = 1;
  gbar(flags, ep); ep++;

  for (int st=0; st<TSTEPS; st++){
    const float* hcur = hb + (size_t)(st&1)*BB*NH;
    float*       hnxt = hb + (size_t)((st+1)&1)*BB*NH;
    float4 gt4 = *(const float4*)(GT + gtrow + st*64 + bg4);

    float acc[4][4];
    #pragma unroll
    for (int j=0;j<4;j++){
      #pragma unroll
      for (int i=0;i<4;i++) acc[j][i]=0.f;
    }

    ISSUE_CHUNK(0,0);
    ISSUE_CHUNK(1,1); WAITVM(8); COMPUTE_CHUNK(0,0);
    ISSUE_CHUNK(2,0); WAITVM(8); COMPUTE_CHUNK(1,1);
    ISSUE_CHUNK(3,1); WAITVM(8); COMPUTE_CHUNK(2,0);
    ISSUE_CHUNK(4,0); WAITVM(8); COMPUTE_CHUNK(3,1);
    ISSUE_CHUNK(5,1); WAITVM(8); COMPUTE_CHUNK(4,0);
    ISSUE_CHUNK(6,0); WAITVM(8); COMPUTE_CHUNK(5,1);
    ISSUE_CHUNK(7,1); WAITVM(8); COMPUTE_CHUNK(6,0);
                      WAITVM(0); COMPUTE_CHUNK(7,1);

    __syncthreads();   // all waves done reading hs before red-alias write
    // K-quarter reduction across waves (red aliases hs buf0)
    *(float4*)&red[kq*1024 + (rg4+0)*64 + bg4] = make_float4(acc[0][0],acc[0][1],acc[0][2],acc[0][3]);
    *(float4*)&red[kq*1024 + (rg4+1)*64 + bg4] = make_float4(acc[1][0],acc[1][1],acc[1][2],acc[1][3]);
    *(float4*)&red[kq*1024 + (rg4+2)*64 + bg4] = make_float4(acc[2][0],acc[2][1],acc[2][2],acc[2][3]);
    *(float4*)&red[kq*1024 + (rg4+3)*64 + bg4] = make_float4(acc[3][0],acc[3][1],acc[3][2],acc[3][3]);
    __syncthreads();
    float4 s0 = *(const float4*)&red[0*1024 + t*4];
    float4 s1 = *(const float4*)&red[1*1024 + t*4];
    float4 s2 = *(const float4*)&red[2*1024 + t*4];
    float4 s3 = *(const float4*)&red[3*1024 + t*4];
    float4 g4 = make_float4(s0.x+s1.x+s2.x+s3.x + gt4.x,
                            s0.y+s1.y+s2.y+s3.y + gt4.y,
                            s0.z+s1.z+s2.z+s3.z + gt4.z,
                            s0.w+s1.w+s2.w+s3.w + gt4.w);
    glds[bg4+0][r] = g4.x;
    glds[bg4+1][r] = g4.y;
    glds[bg4+2][r] = g4.z;
    glds[bg4+3][r] = g4.w;
    __syncthreads();
    float gi = glds[b][0*4+cc];
    float gf = glds[b][1*4+cc];
    float gg = glds[b][2*4+cc];
    float go = glds[b][3*4+cc];
    float cnew = sigmf(gf)*creg + sigmf(gi)*tanhf(gg);
    creg = cnew;
    float hv = sigmf(go)*tanhf(cnew);
    hvals[b][cc] = hv;
    if (st == TSTEPS-1){ hN[b*NH+hc] = hv; cN[b*NH+hc] = creg; }
    __syncthreads();
    {
      int sb = t>>2, sc = t&3;
      float v = hvals[sb][sc];
      __hip_atomic_store(&hnxt[sb*NH + jj*4 + sc], v,
                         __ATOMIC_RELAXED, __HIP_MEMORY_SCOPE_AGENT);
      Y[(size_t)(st*BB+sb)*NH + jj*4 + sc] = v;
    }
    gbar(flags, ep); ep++;
  }
}

// ---------------- top logits ----------------
__global__ __launch_bounds__(256) void k_gemm_top(
    const float* __restrict__ X, const float* __restrict__ W,
    const float* __restrict__ bias, float* __restrict__ C)
{
  __shared__ float Xs[32][68];
  __shared__ float Ws[32][36];
  int n0 = blockIdx.x*64, c0 = blockIdx.y*32;
  int t = threadIdx.x;
  int tm = (t&15)*4;
  int tn = (t>>4)*2;
  int lr = t>>3, lk = (t&7)*4;
  float acc[4][2] = {{0.f}};
  for (int k0=0;k0<NH;k0+=32){
    float4 x0 = *(const float4*)(X + (size_t)(n0+lr)*NH + k0+lk);
    float4 x1 = *(const float4*)(X + (size_t)(n0+lr+32)*NH + k0+lk);
    float4 wv = *(const float4*)(W + (size_t)(k0 + (t>>3))*NCLS + c0 + (t&7)*4);
    __syncthreads();
    Xs[lk+0][lr]=x0.x; Xs[lk+1][lr]=x0.y; Xs[lk+2][lr]=x0.z; Xs[lk+3][lr]=x0.w;
    Xs[lk+0][lr+32]=x1.x; Xs[lk+1][lr+32]=x1.y; Xs[lk+2][lr+32]=x1.z; Xs[lk+3][lr+32]=x1.w;
    *(float4*)&Ws[t>>3][(t&7)*4] = wv;
    __syncthreads();
    #pragma unroll 8
    for (int kk=0;kk<32;kk++){
      float4 av = *(const float4*)&Xs[kk][tm];
      float2 bv = *(const float2*)&Ws[kk][tn];
      acc[0][0] += av.x*bv.x; acc[0][1] += av.x*bv.y;
      acc[1][0] += av.y*bv.x; acc[1][1] += av.y*bv.y;
      acc[2][0] += av.z*bv.x; acc[2][1] += av.z*bv.y;
      acc[3][0] += av.w*bv.x; acc[3][1] += av.w*bv.y;
    }
  }
  float bz0 = bias[c0+tn], bz1 = bias[c0+tn+1];
  #pragma unroll
  for (int i=0;i<4;i++){
    float2 o = make_float2(acc[i][0]+bz0, acc[i][1]+bz1);
    *(float2*)(C + (size_t)(n0+tm+i)*NCLS + c0+tn) = o;
  }
}

// ---------------- per-row top softmax pick ----------------
__global__ void k_top_pick(const float* __restrict__ TL, const int* __restrict__ tg,
                           float* __restrict__ ptop){
  int n = blockIdx.x*4 + (threadIdx.x>>6);
  int lane = threadIdx.x&63;
  const float* row = TL + (size_t)n*NCLS;
  float v[4]; float m = -1e30f;
  #pragma unroll
  for (int q=0;q<4;q++){ int c = lane + q*64; v[q] = (c<NCLS)? row[c] : -1e30f; m = fmaxf(m, v[q]); }
  for (int o=32;o;o>>=1) m = fmaxf(m, __shfl_xor(m,o));
  float s = 0.f;
  #pragma unroll
  for (int q=0;q<4;q++){ int c = lane + q*64; if (c<NCLS) s += expf(v[q]-m); }
  for (int o=32;o;o>>=1) s += __shfl_xor(s,o);
  if (lane==0){ int pt = tg[n]/NPC; ptop[n] = expf(row[pt]-m)/s; }
}

// ---------------- class bucketing ----------------
__global__ void k_zero(int* cnt, int* cur){ int t=threadIdx.x; if(t<NCLS){cnt[t]=0; cur[t]=0;} }
__global__ void k_hist(const int* __restrict__ tg, int* cnt){
  int n = blockIdx.x*256+threadIdx.x;
  if (n<NN) atomicAdd(&cnt[tg[n]/NPC],1);
}
__global__ void k_scan(const int* __restrict__ cnt, int* __restrict__ off){
  if (threadIdx.x==0 && blockIdx.x==0){ int a=0; for(int c=0;c<NCLS;c++){ off[c]=a; a+=cnt[c]; } off[NCLS]=a; }
}
__global__ void k_scatter(const int* __restrict__ tg, const int* __restrict__ off,
                          int* cur, int* __restrict__ perm){
  int n = blockIdx.x*256+threadIdx.x;
  if (n<NN){ int c = tg[n]/NPC; int p = atomicAdd(&cur[c],1); perm[off[c]+p] = n; }
}

// ---------------- per-class bottom GEMM + softmax pick + final product ----------------
__global__ __launch_bounds__(256) void k_bot(
    const float* __restrict__ X, const float* __restrict__ botW, const float* __restrict__ botb,
    const int* __restrict__ tg, const int* __restrict__ off, const int* __restrict__ perm,
    const float* __restrict__ ptop, float* __restrict__ outP)
{
  int cls = blockIdx.x;
  int s = off[cls], e = off[cls+1];
  if (s>=e) return;
  __shared__ float xs[16][NH];
  __shared__ float lg[16][228];
  int t = threadIdx.x;
  const float* Wc = botW + (size_t)cls*NH*NPC;
  for (int base=s; base<e; base+=16){
    int nr = min(16, e-base);
    __syncthreads();
    for (int r=0;r<nr;r++){
      int n = perm[base+r];
      *(float4*)&xs[r][t*4] = *(const float4*)(X + (size_t)n*NH + t*4);
    }
    __syncthreads();
    if (t < NPC){
      float acc[16];
      #pragma unroll
      for (int r=0;r<16;r++) acc[r]=0.f;
      for (int k=0;k<NH;k+=2){
        float w0 = Wc[(size_t)k*NPC + t];
        float w1 = Wc[(size_t)(k+1)*NPC + t];
        #pragma unroll
        for (int r=0;r<16;r++){
          float2 x2 = *(const float2*)&xs[r][k];
          acc[r] += x2.x*w0 + x2.y*w1;
        }
      }
      float bb = botb[(size_t)cls*NPC + t];
      for (int r=0;r<nr;r++) lg[r][t] = acc[r] + bb;
    }
    __syncthreads();
    int wv = t>>6, lane = t&63;
    for (int r=wv; r<nr; r+=4){
      float v[4]; float m=-1e30f;
      #pragma unroll
      for (int q=0;q<4;q++){ int c = lane+q*64; v[q] = (c<NPC)? lg[r][c] : -1e30f; m=fmaxf(m,v[q]); }
      for (int o=32;o;o>>=1) m=fmaxf(m,__shfl_xor(m,o));
      float ss=0.f;
      #pragma unroll
      for (int q=0;q<4;q++){ int c = lane+q*64; if (c<NPC) ss += expf(v[q]-m); }
      for (int o=32;o;o>>=1) ss += __shfl_xor(ss,o);
      if (lane==0){
        int n = perm[base+r]; int pb = tg[n]%NPC;
        outP[n] = ptop[n]*expf(lg[r][pb]-m)/ss;
      }
    }
  }
}

extern "C" void kernel_launch(void* const* d_in, const int* in_sizes, int n_in,
                              void* d_out, int out_size, void* d_ws, size_t ws_size,
                              hipStream_t stream)
{
  const int*   ids  = (const int*)d_in[0];
  const int*   tg   = (const int*)d_in[1];
  const float* h0   = (const float*)d_in[2];
  const float* c0   = (const float*)d_in[3];
  const float* embW = (const float*)d_in[4];
  const float* Wih  = (const float*)d_in[5];
  const float* Whh  = (const float*)d_in[6];
  const float* bih  = (const float*)d_in[7];
  const float* bhh  = (const float*)d_in[8];
  const float* topW = (const float*)d_in[9];
  const float* topb = (const float*)d_in[10];
  const float* botW = (const float*)d_in[11];
  const float* botb = (const float*)d_in[12];
  float* out = (float*)d_out;

  float* X  = (float*)d_ws;                    // [NN][NH]
  float* Yb = X  + (size_t)NN*NH;              // [NN][NH]
  float* GT = Yb + (size_t)NN*NH;              // [G4][NN]
  float* hb = GT + (size_t)G4*NN;              // [2][BB][NH]
  float* TL = hb + 2*(size_t)BB*NH;            // [NN][NCLS]
  float* pt = TL + (size_t)NN*NCLS;            // [NN]
  int* cnt  = (int*)(pt + NN);
  int* off  = cnt + NCLS;
  int* cur  = off + NCLS + 1;
  int* perm = cur + NCLS;
  unsigned* flags = (unsigned*)(perm + NN);    // [256]

  k_embed<<<NN,256,0,stream>>>(ids, embW, X);

  for (int l=0; l<2; l++){
    const float* A   = Wih + (size_t)l*G4*NH;
    const float* Wl  = Whh + (size_t)l*G4*NH;
    const float* bi  = bih + (size_t)l*G4;
    const float* bh  = bhh + (size_t)l*G4;
    const float* Bx  = (l==0)? X : Yb;
    float*       Yo  = (l==0)? Yb : X;
    k_gemm_nt<<<dim3(64,128),256,0,stream>>>(A, Bx, bi, bh, GT, NN);
    const float* h0l = h0 + (size_t)l*BB*NH;
    const float* c0l = c0 + (size_t)l*BB*NH;
    float* hNl = out + NN + (size_t)l*BB*NH;
    float* cNl = out + NN + 2*(size_t)BB*NH + (size_t)l*BB*NH;
    (void)hipMemsetAsync(flags, 0, 256*sizeof(unsigned), stream);
    k_rec<<<256,256,0,stream>>>(GT, Wl, h0l, c0l, hb, Yo, hNl, cNl, flags);
  }

  // X now holds the layer-1 output sequence [NN][NH]
  k_gemm_top<<<dim3(128,7),256,0,stream>>>(X, topW, topb, TL);
  k_top_pick<<<NN/4,256,0,stream>>>(TL, tg, pt);
  k_zero<<<1,256,0,stream>>>(cnt, cur);
  k_hist<<<NN/256,256,0,stream>>>(tg, cnt);
  k_scan<<<1,1,0,stream>>>(cnt, off);
  k_scatter<<<NN/256,256,0,stream>>>(tg, off, cur, perm);
  k_bot<<<NCLS,256,0,stream>>>(X, botW, botb, tg, off, perm, pt, out);
}

// Round 10
// 5490.016 us; speedup vs baseline: 3.8508x; 1.4555x over previous
//
#include <hip/hip_runtime.h>
#include <math.h>

#define NTOK 50257
#define NPC  225
#define NCLS 224
#define NH   1024
#define G4   4096
#define TSTEPS 128
#define BB   64
#define NN   8192

typedef __attribute__((ext_vector_type(8))) short bf16x8;
typedef __attribute__((ext_vector_type(4))) float f32x4;
typedef unsigned long long ull;

__device__ __forceinline__ float sigmf(float x){ return 1.0f/(1.0f+expf(-x)); }

__device__ __forceinline__ unsigned short f2bf(float f){
  unsigned u = __float_as_uint(f);
  unsigned r = u + 0x7fffu + ((u>>16)&1u);
  return (unsigned short)(r>>16);
}
__device__ __forceinline__ float bf2f(unsigned short s){
  return __uint_as_float(((unsigned)s)<<16);
}
__device__ __forceinline__ ull pack4(unsigned short a, unsigned short b,
                                     unsigned short c, unsigned short d){
  return (ull)a | ((ull)b<<16) | ((ull)c<<32) | ((ull)d<<48);
}

// global->LDS DMA, aux literal: 17 = SC0|SC1 (agent-coherent read from IF$)
template<int AUX>
__device__ __forceinline__ void gl2lds16(const void* g, void* l){
  __builtin_amdgcn_global_load_lds(
      (const __attribute__((address_space(1))) unsigned int*)(g),
      (__attribute__((address_space(3))) unsigned int*)(l), 16, 0, AUX);
}

// flag-array grid barrier, fence-free (R9-proven): release = vmcnt(0) drain of
// agent-scope write-through stores; no buffer_wbl2/inv. 1 block/CU x 256.
__device__ __forceinline__ void gbar(unsigned* flags, unsigned ep){
  asm volatile("s_waitcnt vmcnt(0) lgkmcnt(0)" ::: "memory");
  __syncthreads();
  if (threadIdx.x==0)
    __hip_atomic_store(&flags[blockIdx.x], ep, __ATOMIC_RELAXED, __HIP_MEMORY_SCOPE_AGENT);
  while (__hip_atomic_load(&flags[threadIdx.x], __ATOMIC_RELAXED, __HIP_MEMORY_SCOPE_AGENT) < ep)
    __builtin_amdgcn_s_sleep(2);
  __syncthreads();
}

// ---------------- embedding gather ----------------
__global__ void k_embed(const int* __restrict__ ids, const float* __restrict__ embW,
                        float* __restrict__ X){
  int n = blockIdx.x;
  int t = threadIdx.x;
  const float4* s = (const float4*)(embW + (size_t)ids[n]*NH);
  float4* d = (float4*)(X + (size_t)n*NH);
  d[t] = s[t];
}

// ---------------- C[4096][Nd] = A[4096][1024] * B[Nd][1024]^T + (bi+bh) ----------------
__global__ __launch_bounds__(256) void k_gemm_nt(
    const float* __restrict__ A, const float* __restrict__ B,
    const float* __restrict__ bi, const float* __restrict__ bh,
    float* __restrict__ C, int Nd)
{
  __shared__ float As[32][68];
  __shared__ float Bs[32][68];
  int m0 = blockIdx.x*64, n0 = blockIdx.y*64;
  int t = threadIdx.x;
  int tm = (t&15)*4, tn = (t>>4)*4;
  int lr = t>>3, lk = (t&7)*4;
  float acc[4][4] = {{0.f}};
  for (int k0=0;k0<NH;k0+=32){
    float4 a0 = *(const float4*)(A + (size_t)(m0+lr)*NH + k0+lk);
    float4 a1 = *(const float4*)(A + (size_t)(m0+lr+32)*NH + k0+lk);
    float4 b0 = *(const float4*)(B + (size_t)(n0+lr)*NH + k0+lk);
    float4 b1 = *(const float4*)(B + (size_t)(n0+lr+32)*NH + k0+lk);
    __syncthreads();
    As[lk+0][lr]=a0.x; As[lk+1][lr]=a0.y; As[lk+2][lr]=a0.z; As[lk+3][lr]=a0.w;
    As[lk+0][lr+32]=a1.x; As[lk+1][lr+32]=a1.y; As[lk+2][lr+32]=a1.z; As[lk+3][lr+32]=a1.w;
    Bs[lk+0][lr]=b0.x; Bs[lk+1][lr]=b0.y; Bs[lk+2][lr]=b0.z; Bs[lk+3][lr]=b0.w;
    Bs[lk+0][lr+32]=b1.x; Bs[lk+1][lr+32]=b1.y; Bs[lk+2][lr+32]=b1.z; Bs[lk+3][lr+32]=b1.w;
    __syncthreads();
    #pragma unroll 8
    for (int kk=0;kk<32;kk++){
      float4 av = *(const float4*)&As[kk][tm];
      float4 bv = *(const float4*)&Bs[kk][tn];
      acc[0][0] += av.x*bv.x; acc[0][1] += av.x*bv.y; acc[0][2] += av.x*bv.z; acc[0][3] += av.x*bv.w;
      acc[1][0] += av.y*bv.x; acc[1][1] += av.y*bv.y; acc[1][2] += av.y*bv.z; acc[1][3] += av.y*bv.w;
      acc[2][0] += av.z*bv.x; acc[2][1] += av.z*bv.y; acc[2][2] += av.z*bv.z; acc[2][3] += av.z*bv.w;
      acc[3][0] += av.w*bv.x; acc[3][1] += av.w*bv.y; acc[3][2] += av.w*bv.z; acc[3][3] += av.w*bv.w;
    }
  }
  #pragma unroll
  for (int i=0;i<4;i++){
    int m = m0+tm+i;
    float bias = bi[m]+bh[m];
    float4 o = make_float4(acc[i][0]+bias, acc[i][1]+bias, acc[i][2]+bias, acc[i][3]+bias);
    *(float4*)(C + (size_t)m*Nd + n0+tn) = o;
  }
}

// ---------------- persistent LSTM recurrence: split-bf16 MFMA core ----------------
// Block jj owns gate rows r=g*4+col for cols jj*4..+3. W kept in LDS as bf16
// hi/lo, granule-swizzled (^row&7). h exchanged via global bf16 hi/lo planes
// (agent-atomic 8B stores -> aux=17 DMA reads). Wave w computes the full-K
// 16x16 D tile for batches w*16..+15: 16 chunks of 64k, 4-deep DMA pipeline,
// 3 MFMA passes per ktile (hi*hi + hi*lo + lo*hi), fp32 accumulators.

#define WAITVM(N) asm volatile("s_waitcnt vmcnt(" #N ")" ::: "memory")

#define ISSUE_CHUNK(c, d) { \
  asm volatile("s_waitcnt lgkmcnt(0)" ::: "memory"); \
  const int hb_ = hreg + (d)*1024; \
  _Pragma("unroll") \
  for (int i_=0;i_<2;i_++){ \
    int rl_ = i_*8 + (lane>>3); \
    int sg_ = (lane&7) ^ (rl_&7); \
    size_t so_ = hsrc + (size_t)(w16 + rl_)*1024 + (size_t)(c)*64 + sg_*8; \
    gl2lds16<17>(hbH + so_, (void*)&hcH[hb_ + i_*512]); \
    gl2lds16<17>(hbL + so_, (void*)&hcL[hb_ + i_*512]); \
  } }

#define COMPUTE_CHUNK(c, d) { \
  const int hb_ = hreg + (d)*1024; \
  _Pragma("unroll") \
  for (int k2_=0;k2_<2;k2_++){ \
    int kidx_ = (c)*2 + k2_; \
    int ap_ = (((kidx_*4 + kg) ^ l7)<<3); \
    bf16x8 aH_ = *(const bf16x8*)&wldsH[l15*1024 + ap_]; \
    bf16x8 aL_ = *(const bf16x8*)&wldsL[l15*1024 + ap_]; \
    int bp_ = (((k2_*4 + kg) ^ l7)<<3); \
    bf16x8 bH_ = *(const bf16x8*)&hcH[hb_ + l15*64 + bp_]; \
    bf16x8 bL_ = *(const bf16x8*)&hcL[hb_ + l15*64 + bp_]; \
    accA = __builtin_amdgcn_mfma_f32_16x16x32_bf16(aH_, bH_, accA, 0,0,0); \
    accB = __builtin_amdgcn_mfma_f32_16x16x32_bf16(aH_, bL_, accB, 0,0,0); \
    accC = __builtin_amdgcn_mfma_f32_16x16x32_bf16(aL_, bH_, accC, 0,0,0); \
  } }

__global__ __launch_bounds__(256,1) void k_rec(
    const float* __restrict__ GT, const float* __restrict__ Wh,
    const float* __restrict__ h0, const float* __restrict__ c0,
    unsigned short* __restrict__ hbH, unsigned short* __restrict__ hbL,
    float* __restrict__ Y,
    float* __restrict__ hN, float* __restrict__ cN,
    unsigned* flags)
{
  __shared__ unsigned short wldsH[16*1024];  // 32 KB, swizzled
  __shared__ unsigned short wldsL[16*1024];  // 32 KB
  __shared__ unsigned short hcH[16*1024];    // 32 KB: [wave][4 buf][16][64]
  __shared__ unsigned short hcL[16*1024];    // 32 KB
  __shared__ float glds[64][20];             // 5 KB
  __shared__ float hvals[64][5];             // 1.25 KB  (total 137,472 B)

  int jj = blockIdx.x, t = threadIdx.x;
  int jj4 = jj*4;

  // ---- W -> bf16 hi/lo, swizzled store (granule ^= row&7) ----
  for (int rr=0; rr<16; rr++){
    int grow = (rr>>2)*NH + jj4 + (rr&3);
    float4 w4 = *(const float4*)(Wh + (size_t)grow*NH + t*4);
    unsigned short h0_=f2bf(w4.x), h1_=f2bf(w4.y), h2_=f2bf(w4.z), h3_=f2bf(w4.w);
    unsigned short l0_=f2bf(w4.x-bf2f(h0_)), l1_=f2bf(w4.y-bf2f(h1_));
    unsigned short l2_=f2bf(w4.z-bf2f(h2_)), l3_=f2bf(w4.w-bf2f(h3_));
    int us = rr*1024 + (((t>>1) ^ (rr&7))<<3) + ((t&1)<<2);
    *(ull*)&wldsH[us] = pack4(h0_,h1_,h2_,h3_);
    *(ull*)&wldsL[us] = pack4(l0_,l1_,l2_,l3_);
  }

  // pointwise mapping
  int b = t&63, cc = t>>6;
  int hc = jj4 + cc;
  // MFMA mapping
  int lane = t&63, w = t>>6, w16 = w*16;
  int l15 = lane&15, l7 = lane&7, kg = lane>>4;
  int hreg = w*4096;   // wave region base (ushorts) in hcH/hcL

  float creg = c0[b*NH + hc];
  // h0 -> bf16 planes (buffer 0)
  hvals[b][cc] = h0[b*NH + hc];
  __syncthreads();
  {
    int sb = t&63, which = t>>6;
    if (which<2){
      float v0=hvals[sb][0], v1=hvals[sb][1], v2=hvals[sb][2], v3=hvals[sb][3];
      unsigned short u0=f2bf(v0), u1=f2bf(v1), u2=f2bf(v2), u3=f2bf(v3);
      ull pv = (which==0) ? pack4(u0,u1,u2,u3)
             : pack4(f2bf(v0-bf2f(u0)), f2bf(v1-bf2f(u1)),
                     f2bf(v2-bf2f(u2)), f2bf(v3-bf2f(u3)));
      unsigned short* pl = (which==0) ? hbH : hbL;
      __hip_atomic_store((ull*)&pl[(size_t)sb*1024 + jj4], pv,
                         __ATOMIC_RELAXED, __HIP_MEMORY_SCOPE_AGENT);
    }
  }
  unsigned ep = 1;
  gbar(flags, ep); ep++;

  for (int st=0; st<TSTEPS; st++){
    const size_t hsrc  = (size_t)(st&1)*65536;
    const size_t hdstg = (size_t)((st+1)&1)*65536;

    // gate-bias loads (pointwise mapping), pinned BEFORE DMA issues so the
    // vmcnt ledger stays exact (they retire first, covered by first WAITVM)
    float gtv0 = GT[((size_t)0*NH + jj4 + cc)*NN + st*64 + b];
    float gtv1 = GT[((size_t)1*NH + jj4 + cc)*NN + st*64 + b];
    float gtv2 = GT[((size_t)2*NH + jj4 + cc)*NN + st*64 + b];
    float gtv3 = GT[((size_t)3*NH + jj4 + cc)*NN + st*64 + b];
    __builtin_amdgcn_sched_barrier(0);

    f32x4 accA = {0.f,0.f,0.f,0.f};
    f32x4 accB = {0.f,0.f,0.f,0.f};
    f32x4 accC = {0.f,0.f,0.f,0.f};

    ISSUE_CHUNK(0,0); ISSUE_CHUNK(1,1); ISSUE_CHUNK(2,2);
    for (int c=0;c<13;c++){
      ISSUE_CHUNK(c+3, (c+3)&3);
      WAITVM(12);
      COMPUTE_CHUNK(c, c&3);
    }
    WAITVM(8);  COMPUTE_CHUNK(13,1);
    WAITVM(4);  COMPUTE_CHUNK(14,2);
    WAITVM(0);  COMPUTE_CHUNK(15,3);

    // D exchange: lane holds rows kg*4..+3 (gate rows) for batch w16+l15
    glds[w16 + l15][kg*4+0] = accA[0]+accB[0]+accC[0];
    glds[w16 + l15][kg*4+1] = accA[1]+accB[1]+accC[1];
    glds[w16 + l15][kg*4+2] = accA[2]+accB[2]+accC[2];
    glds[w16 + l15][kg*4+3] = accA[3]+accB[3]+accC[3];
    __syncthreads();
    float gi = glds[b][0 +cc] + gtv0;
    float gf = glds[b][4 +cc] + gtv1;
    float gg = glds[b][8 +cc] + gtv2;
    float go = glds[b][12+cc] + gtv3;
    float cnew = sigmf(gf)*creg + sigmf(gi)*tanhf(gg);
    creg = cnew;
    float hv = sigmf(go)*tanhf(cnew);
    hvals[b][cc] = hv;
    if (st == TSTEPS-1){ hN[b*NH+hc] = hv; cN[b*NH+hc] = creg; }
    __syncthreads();
    {
      int sb = t&63, which = t>>6;
      if (which<2){
        float v0=hvals[sb][0], v1=hvals[sb][1], v2=hvals[sb][2], v3=hvals[sb][3];
        unsigned short u0=f2bf(v0), u1=f2bf(v1), u2=f2bf(v2), u3=f2bf(v3);
        ull pv = (which==0) ? pack4(u0,u1,u2,u3)
               : pack4(f2bf(v0-bf2f(u0)), f2bf(v1-bf2f(u1)),
                       f2bf(v2-bf2f(u2)), f2bf(v3-bf2f(u3)));
        unsigned short* pl = (which==0) ? hbH : hbL;
        __hip_atomic_store((ull*)&pl[hdstg + (size_t)sb*1024 + jj4], pv,
                           __ATOMIC_RELAXED, __HIP_MEMORY_SCOPE_AGENT);
      } else if (which==2){
        float4 yv = make_float4(hvals[sb][0],hvals[sb][1],hvals[sb][2],hvals[sb][3]);
        *(float4*)(Y + (size_t)(st*BB+sb)*NH + jj4) = yv;
      }
    }
    gbar(flags, ep); ep++;
  }
}

// ---------------- top logits ----------------
__global__ __launch_bounds__(256) void k_gemm_top(
    const float* __restrict__ X, const float* __restrict__ W,
    const float* __restrict__ bias, float* __restrict__ C)
{
  __shared__ float Xs[32][68];
  __shared__ float Ws[32][36];
  int n0 = blockIdx.x*64, c0 = blockIdx.y*32;
  int t = threadIdx.x;
  int tm = (t&15)*4;
  int tn = (t>>4)*2;
  int lr = t>>3, lk = (t&7)*4;
  float acc[4][2] = {{0.f}};
  for (int k0=0;k0<NH;k0+=32){
    float4 x0 = *(const float4*)(X + (size_t)(n0+lr)*NH + k0+lk);
    float4 x1 = *(const float4*)(X + (size_t)(n0+lr+32)*NH + k0+lk);
    float4 wv = *(const float4*)(W + (size_t)(k0 + (t>>3))*NCLS + c0 + (t&7)*4);
    __syncthreads();
    Xs[lk+0][lr]=x0.x; Xs[lk+1][lr]=x0.y; Xs[lk+2][lr]=x0.z; Xs[lk+3][lr]=x0.w;
    Xs[lk+0][lr+32]=x1.x; Xs[lk+1][lr+32]=x1.y; Xs[lk+2][lr+32]=x1.z; Xs[lk+3][lr+32]=x1.w;
    *(float4*)&Ws[t>>3][(t&7)*4] = wv;
    __syncthreads();
    #pragma unroll 8
    for (int kk=0;kk<32;kk++){
      float4 av = *(const float4*)&Xs[kk][tm];
      float2 bv = *(const float2*)&Ws[kk][tn];
      acc[0][0] += av.x*bv.x; acc[0][1] += av.x*bv.y;
      acc[1][0] += av.y*bv.x; acc[1][1] += av.y*bv.y;
      acc[2][0] += av.z*bv.x; acc[2][1] += av.z*bv.y;
      acc[3][0] += av.w*bv.x; acc[3][1] += av.w*bv.y;
    }
  }
  float bz0 = bias[c0+tn], bz1 = bias[c0+tn+1];
  #pragma unroll
  for (int i=0;i<4;i++){
    float2 o = make_float2(acc[i][0]+bz0, acc[i][1]+bz1);
    *(float2*)(C + (size_t)(n0+tm+i)*NCLS + c0+tn) = o;
  }
}

// ---------------- per-row top softmax pick ----------------
__global__ void k_top_pick(const float* __restrict__ TL, const int* __restrict__ tg,
                           float* __restrict__ ptop){
  int n = blockIdx.x*4 + (threadIdx.x>>6);
  int lane = threadIdx.x&63;
  const float* row = TL + (size_t)n*NCLS;
  float v[4]; float m = -1e30f;
  #pragma unroll
  for (int q=0;q<4;q++){ int c = lane + q*64; v[q] = (c<NCLS)? row[c] : -1e30f; m = fmaxf(m, v[q]); }
  for (int o=32;o;o>>=1) m = fmaxf(m, __shfl_xor(m,o));
  float s = 0.f;
  #pragma unroll
  for (int q=0;q<4;q++){ int c = lane + q*64; if (c<NCLS) s += expf(v[q]-m); }
  for (int o=32;o;o>>=1) s += __shfl_xor(s,o);
  if (lane==0){ int pt = tg[n]/NPC; ptop[n] = expf(row[pt]-m)/s; }
}

// ---------------- class bucketing ----------------
__global__ void k_zero(int* cnt, int* cur){ int t=threadIdx.x; if(t<NCLS){cnt[t]=0; cur[t]=0;} }
__global__ void k_hist(const int* __restrict__ tg, int* cnt){
  int n = blockIdx.x*256+threadIdx.x;
  if (n<NN) atomicAdd(&cnt[tg[n]/NPC],1);
}
__global__ void k_scan(const int* __restrict__ cnt, int* __restrict__ off){
  if (threadIdx.x==0 && blockIdx.x==0){ int a=0; for(int c=0;c<NCLS;c++){ off[c]=a; a+=cnt[c]; } off[NCLS]=a; }
}
__global__ void k_scatter(const int* __restrict__ tg, const int* __restrict__ off,
                          int* cur, int* __restrict__ perm){
  int n = blockIdx.x*256+threadIdx.x;
  if (n<NN){ int c = tg[n]/NPC; int p = atomicAdd(&cur[c],1); perm[off[c]+p] = n; }
}

// ---------------- per-class bottom GEMM + softmax pick + final product ----------------
__global__ __launch_bounds__(256) void k_bot(
    const float* __restrict__ X, const float* __restrict__ botW, const float* __restrict__ botb,
    const int* __restrict__ tg, const int* __restrict__ off, const int* __restrict__ perm,
    const float* __restrict__ ptop, float* __restrict__ outP)
{
  int cls = blockIdx.x;
  int s = off[cls], e = off[cls+1];
  if (s>=e) return;
  __shared__ float xs[16][NH];
  __shared__ float lg[16][228];
  int t = threadIdx.x;
  const float* Wc = botW + (size_t)cls*NH*NPC;
  for (int base=s; base<e; base+=16){
    int nr = min(16, e-base);
    __syncthreads();
    for (int r=0;r<nr;r++){
      int n = perm[base+r];
      *(float4*)&xs[r][t*4] = *(const float4*)(X + (size_t)n*NH + t*4);
    }
    __syncthreads();
    if (t < NPC){
      float acc[16];
      #pragma unroll
      for (int r=0;r<16;r++) acc[r]=0.f;
      for (int k=0;k<NH;k+=2){
        float w0 = Wc[(size_t)k*NPC + t];
        float w1 = Wc[(size_t)(k+1)*NPC + t];
        #pragma unroll
        for (int r=0;r<16;r++){
          float2 x2 = *(const float2*)&xs[r][k];
          acc[r] += x2.x*w0 + x2.y*w1;
        }
      }
      float bb = botb[(size_t)cls*NPC + t];
      for (int r=0;r<nr;r++) lg[r][t] = acc[r] + bb;
    }
    __syncthreads();
    int wv = t>>6, lane = t&63;
    for (int r=wv; r<nr; r+=4){
      float v[4]; float m=-1e30f;
      #pragma unroll
      for (int q=0;q<4;q++){ int c = lane+q*64; v[q] = (c<NPC)? lg[r][c] : -1e30f; m=fmaxf(m,v[q]); }
      for (int o=32;o;o>>=1) m=fmaxf(m,__shfl_xor(m,o));
      float ss=0.f;
      #pragma unroll
      for (int q=0;q<4;q++){ int c = lane+q*64; if (c<NPC) ss += expf(v[q]-m); }
      for (int o=32;o;o>>=1) ss += __shfl_xor(ss,o);
      if (lane==0){
        int n = perm[base+r]; int pb = tg[n]%NPC;
        outP[n] = ptop[n]*expf(lg[r][pb]-m)/ss;
      }
    }
  }
}

extern "C" void kernel_launch(void* const* d_in, const int* in_sizes, int n_in,
                              void* d_out, int out_size, void* d_ws, size_t ws_size,
                              hipStream_t stream)
{
  const int*   ids  = (const int*)d_in[0];
  const int*   tg   = (const int*)d_in[1];
  const float* h0   = (const float*)d_in[2];
  const float* c0   = (const float*)d_in[3];
  const float* embW = (const float*)d_in[4];
  const float* Wih  = (const float*)d_in[5];
  const float* Whh  = (const float*)d_in[6];
  const float* bih  = (const float*)d_in[7];
  const float* bhh  = (const float*)d_in[8];
  const float* topW = (const float*)d_in[9];
  const float* topb = (const float*)d_in[10];
  const float* botW = (const float*)d_in[11];
  const float* botb = (const float*)d_in[12];
  float* out = (float*)d_out;

  float* X  = (float*)d_ws;                    // [NN][NH]
  float* Yb = X  + (size_t)NN*NH;              // [NN][NH]
  float* GT = Yb + (size_t)NN*NH;              // [G4][NN]
  float* hb = GT + (size_t)G4*NN;              // 512 KB: bf16 hi/lo planes
  float* TL = hb + 2*(size_t)BB*NH;            // [NN][NCLS]
  float* pt = TL + (size_t)NN*NCLS;            // [NN]
  int* cnt  = (int*)(pt + NN);
  int* off  = cnt + NCLS;
  int* cur  = off + NCLS + 1;
  int* perm = cur + NCLS;
  unsigned* flags = (unsigned*)(perm + NN);    // [256]

  unsigned short* hbH = (unsigned short*)hb;   // [2][64][1024] bf16 hi
  unsigned short* hbL = hbH + 2*BB*NH;         // [2][64][1024] bf16 lo

  k_embed<<<NN,256,0,stream>>>(ids, embW, X);

  for (int l=0; l<2; l++){
    const float* A   = Wih + (size_t)l*G4*NH;
    const float* Wl  = Whh + (size_t)l*G4*NH;
    const float* bi  = bih + (size_t)l*G4;
    const float* bh  = bhh + (size_t)l*G4;
    const float* Bx  = (l==0)? X : Yb;
    float*       Yo  = (l==0)? Yb : X;
    k_gemm_nt<<<dim3(64,128),256,0,stream>>>(A, Bx, bi, bh, GT, NN);
    const float* h0l = h0 + (size_t)l*BB*NH;
    const float* c0l = c0 + (size_t)l*BB*NH;
    float* hNl = out + NN + (size_t)l*BB*NH;
    float* cNl = out + NN + 2*(size_t)BB*NH + (size_t)l*BB*NH;
    (void)hipMemsetAsync(flags, 0, 256*sizeof(unsigned), stream);
    k_rec<<<256,256,0,stream>>>(GT, Wl, h0l, c0l, hbH, hbL, Yo, hNl, cNl, flags);
  }

  // X now holds the layer-1 output sequence [NN][NH]
  k_gemm_top<<<dim3(128,7),256,0,stream>>>(X, topW, topb, TL);
  k_top_pick<<<NN/4,256,0,stream>>>(TL, tg, pt);
  k_zero<<<1,256,0,stream>>>(cnt, cur);
  k_hist<<<NN/256,256,0,stream>>>(tg, cnt);
  k_scan<<<1,1,0,stream>>>(cnt, off);
  k_scatter<<<NN/256,256,0,stream>>>(tg, off, cur, perm);
  k_bot<<<NCLS,256,0,stream>>>(X, botW, botb, tg, off, perm, pt, out);
}

// Round 11
// 4187.574 us; speedup vs baseline: 5.0484x; 1.3110x over previous
//
#include <hip/hip_runtime.h>
#include <math.h>

#define NTOK 50257
#define NPC  225
#define NCLS 224
#define NH   1024
#define G4   4096
#define TSTEPS 128
#define BB   64
#define NN   8192

typedef __attribute__((ext_vector_type(8))) short bf16x8;
typedef __attribute__((ext_vector_type(4))) float f32x4;
typedef unsigned long long ull;

__device__ __forceinline__ float sigmf(float x){ return 1.0f/(1.0f+expf(-x)); }

__device__ __forceinline__ unsigned short f2bf(float f){
  unsigned u = __float_as_uint(f);
  unsigned r = u + 0x7fffu + ((u>>16)&1u);
  return (unsigned short)(r>>16);
}
__device__ __forceinline__ float bf2f(unsigned short s){
  return __uint_as_float(((unsigned)s)<<16);
}
__device__ __forceinline__ ull pack4(unsigned short a, unsigned short b,
                                     unsigned short c, unsigned short d){
  return (ull)a | ((ull)b<<16) | ((ull)c<<32) | ((ull)d<<48);
}

// global->LDS DMA, aux literal (17 = SC0|SC1 agent-coherent; 0 = normal cached)
template<int AUX>
__device__ __forceinline__ void gl2lds16(const void* g, void* l){
  __builtin_amdgcn_global_load_lds(
      (const __attribute__((address_space(1))) unsigned int*)(g),
      (__attribute__((address_space(3))) unsigned int*)(l), 16, 0, AUX);
}

// flag-array grid barrier, fence-free (R9-proven)
__device__ __forceinline__ void gbar(unsigned* flags, unsigned ep){
  asm volatile("s_waitcnt vmcnt(0) lgkmcnt(0)" ::: "memory");
  __syncthreads();
  if (threadIdx.x==0)
    __hip_atomic_store(&flags[blockIdx.x], ep, __ATOMIC_RELAXED, __HIP_MEMORY_SCOPE_AGENT);
  while (__hip_atomic_load(&flags[threadIdx.x], __ATOMIC_RELAXED, __HIP_MEMORY_SCOPE_AGENT) < ep)
    __builtin_amdgcn_s_sleep(2);
  __syncthreads();
}

// ---------------- embedding gather ----------------
__global__ void k_embed(const int* __restrict__ ids, const float* __restrict__ embW,
                        float* __restrict__ X){
  int n = blockIdx.x;
  int t = threadIdx.x;
  const float4* s = (const float4*)(embW + (size_t)ids[n]*NH);
  float4* d = (float4*)(X + (size_t)n*NH);
  d[t] = s[t];
}

// ---------------- fp32 -> bf16 hi/lo plane conversion (linear layout) ----------------
__global__ __launch_bounds__(256) void k_cvt(const float* __restrict__ src,
    unsigned short* __restrict__ dh, unsigned short* __restrict__ dl){
  int gid = blockIdx.x*256 + threadIdx.x;   // one 8-elem granule per thread
  const float4* s = (const float4*)src + (size_t)gid*2;
  float4 a = s[0], b = s[1];
  unsigned short h0=f2bf(a.x),h1=f2bf(a.y),h2=f2bf(a.z),h3=f2bf(a.w);
  unsigned short h4=f2bf(b.x),h5=f2bf(b.y),h6=f2bf(b.z),h7=f2bf(b.w);
  ull* dh8 = (ull*)(dh + (size_t)gid*8);
  dh8[0] = pack4(h0,h1,h2,h3); dh8[1] = pack4(h4,h5,h6,h7);
  ull* dl8 = (ull*)(dl + (size_t)gid*8);
  dl8[0] = pack4(f2bf(a.x-bf2f(h0)), f2bf(a.y-bf2f(h1)), f2bf(a.z-bf2f(h2)), f2bf(a.w-bf2f(h3)));
  dl8[1] = pack4(f2bf(b.x-bf2f(h4)), f2bf(b.y-bf2f(h5)), f2bf(b.z-bf2f(h6)), f2bf(b.w-bf2f(h7)));
}

// ---------------- split-bf16 MFMA GEMM: C[4096][8192] = A.B^T + (bi+bh) ----------------
// Effective K' = 3072: kt 0..15 Ah.Bh, 16..31 Ah.Bl, 32..47 Al.Bh (3-pass split-bf16).
// 128x128 tile, BK=64, global_load_lds w16 double-buffered, source-XOR granule swizzle.
#define STAGE3(kt, bf) { \
  const unsigned short* Ap_ = ((kt)<32)? Ah : Al; \
  const unsigned short* Bp_ = (((kt)<16)||((kt)>=32))? Bh : Bl; \
  int ktp_ = (kt)&15; \
  _Pragma("unroll") \
  for (int i_=0;i_<4;i_++){ \
    int row_ = i_*32 + w*8 + (lane>>3); \
    int gs_ = (lane&7) ^ (row_&7); \
    gl2lds16<0>(Ap_ + (size_t)(m0+row_)*1024 + ktp_*64 + gs_*8, \
                (void*)&As[bf][(i_*256 + w*64)*8]); \
  } \
  _Pragma("unroll") \
  for (int i_=0;i_<4;i_++){ \
    int row_ = i_*32 + w*8 + (lane>>3); \
    int gs_ = (lane&7) ^ (row_&7); \
    gl2lds16<0>(Bp_ + (size_t)(n0+row_)*1024 + ktp_*64 + gs_*8, \
                (void*)&Bs[bf][(i_*256 + w*64)*8]); \
  } }

#define COMP3(bf) { \
  _Pragma("unroll") \
  for (int kh_=0;kh_<2;kh_++){ \
    bf16x8 af_[4], bfr_[4]; \
    _Pragma("unroll") \
    for (int f_=0; f_<4; f_++){ \
      int ar_ = wm + f_*16 + l15; \
      int ag_ = (kh_*4+kg) ^ (ar_&7); \
      af_[f_] = *(const bf16x8*)&As[bf][(ar_*8 + ag_)*8]; \
      int br_ = wn + f_*16 + l15; \
      int bg_ = (kh_*4+kg) ^ (br_&7); \
      bfr_[f_] = *(const bf16x8*)&Bs[bf][(br_*8 + bg_)*8]; \
    } \
    _Pragma("unroll") \
    for (int fa_=0; fa_<4; fa_++) \
      _Pragma("unroll") \
      for (int fb_=0; fb_<4; fb_++) \
        acc[fa_][fb_] = __builtin_amdgcn_mfma_f32_16x16x32_bf16(af_[fa_], bfr_[fb_], acc[fa_][fb_], 0,0,0); \
  } }

#define WAITVM(N) asm volatile("s_waitcnt vmcnt(" #N ")" ::: "memory")

__global__ __launch_bounds__(256,1) void k_gemm3(
    const unsigned short* __restrict__ Ah, const unsigned short* __restrict__ Al,
    const unsigned short* __restrict__ Bh, const unsigned short* __restrict__ Bl,
    const float* __restrict__ bi, const float* __restrict__ bh,
    float* __restrict__ C)
{
  __shared__ unsigned short As[2][128*64];   // 16 KB per buf
  __shared__ unsigned short Bs[2][128*64];
  int m0 = blockIdx.x*128, n0 = blockIdx.y*128;
  int t = threadIdx.x, lane = t&63, w = t>>6;
  int wm = (w>>1)*64, wn = (w&1)*64;
  int l15 = lane&15, kg = lane>>4;
  f32x4 acc[4][4];
  #pragma unroll
  for (int i=0;i<4;i++){
    #pragma unroll
    for (int j=0;j<4;j++) acc[i][j] = (f32x4){0.f,0.f,0.f,0.f};
  }

  STAGE3(0,0);
  for (int kt=0; kt<48; kt++){
    __syncthreads();                         // all waves done reading buf being overwritten
    if (kt<47){ STAGE3(kt+1, (kt+1)&1); WAITVM(8); }
    else      { WAITVM(0); }
    __syncthreads();                         // all waves' DMA for buf[kt&1] landed
    COMP3(kt&1);
  }

  // epilogue: D row (kg*4+i) = A row, col l15 = B row
  #pragma unroll
  for (int fa=0; fa<4; fa++){
    #pragma unroll
    for (int i=0;i<4;i++){
      int m = m0 + wm + fa*16 + kg*4 + i;
      float bias = bi[m] + bh[m];
      #pragma unroll
      for (int fb=0; fb<4; fb++){
        C[(size_t)m*NN + n0 + wn + fb*16 + l15] = acc[fa][fb][i] + bias;
      }
    }
  }
}

// ---------------- persistent LSTM recurrence (R10, unchanged) ----------------
#define HS(bf,kq,row,col) hsraw[((bf)<<13) + ((kq)<<11) + ((row)<<5) + (col)]

#define ISSUE_CHUNK(c, d) { \
  asm volatile("s_waitcnt lgkmcnt(0)" ::: "memory"); \
  const int hb_ = hreg + (d)*1024; \
  _Pragma("unroll") \
  for (int i_=0;i_<2;i_++){ \
    int rl_ = i_*8 + (lane>>3); \
    int sg_ = (lane&7) ^ (rl_&7); \
    size_t so_ = hsrc + (size_t)(w16 + rl_)*1024 + (size_t)(c)*64 + sg_*8; \
    gl2lds16<17>(hbH + so_, (void*)&hcH[hb_ + i_*512]); \
    gl2lds16<17>(hbL + so_, (void*)&hcL[hb_ + i_*512]); \
  } }

#define COMPUTE_CHUNK(c, d) { \
  const int hb_ = hreg + (d)*1024; \
  _Pragma("unroll") \
  for (int k2_=0;k2_<2;k2_++){ \
    int kidx_ = (c)*2 + k2_; \
    int ap_ = (((kidx_*4 + kg) ^ l7)<<3); \
    bf16x8 aH_ = *(const bf16x8*)&wldsH[l15*1024 + ap_]; \
    bf16x8 aL_ = *(const bf16x8*)&wldsL[l15*1024 + ap_]; \
    int bp_ = (((k2_*4 + kg) ^ l7)<<3); \
    bf16x8 bH_ = *(const bf16x8*)&hcH[hb_ + l15*64 + bp_]; \
    bf16x8 bL_ = *(const bf16x8*)&hcL[hb_ + l15*64 + bp_]; \
    accA = __builtin_amdgcn_mfma_f32_16x16x32_bf16(aH_, bH_, accA, 0,0,0); \
    accB = __builtin_amdgcn_mfma_f32_16x16x32_bf16(aH_, bL_, accB, 0,0,0); \
    accC = __builtin_amdgcn_mfma_f32_16x16x32_bf16(aL_, bH_, accC, 0,0,0); \
  } }

__global__ __launch_bounds__(256,1) void k_rec(
    const float* __restrict__ GT, const float* __restrict__ Wh,
    const float* __restrict__ h0, const float* __restrict__ c0,
    unsigned short* __restrict__ hbH, unsigned short* __restrict__ hbL,
    float* __restrict__ Y,
    float* __restrict__ hN, float* __restrict__ cN,
    unsigned* flags)
{
  __shared__ unsigned short wldsH[16*1024];
  __shared__ unsigned short wldsL[16*1024];
  __shared__ unsigned short hcH[16*1024];
  __shared__ unsigned short hcL[16*1024];
  __shared__ float glds[64][20];
  __shared__ float hvals[64][5];

  int jj = blockIdx.x, t = threadIdx.x;
  int jj4 = jj*4;

  for (int rr=0; rr<16; rr++){
    int grow = (rr>>2)*NH + jj4 + (rr&3);
    float4 w4 = *(const float4*)(Wh + (size_t)grow*NH + t*4);
    unsigned short h0_=f2bf(w4.x), h1_=f2bf(w4.y), h2_=f2bf(w4.z), h3_=f2bf(w4.w);
    unsigned short l0_=f2bf(w4.x-bf2f(h0_)), l1_=f2bf(w4.y-bf2f(h1_));
    unsigned short l2_=f2bf(w4.z-bf2f(h2_)), l3_=f2bf(w4.w-bf2f(h3_));
    int us = rr*1024 + (((t>>1) ^ (rr&7))<<3) + ((t&1)<<2);
    *(ull*)&wldsH[us] = pack4(h0_,h1_,h2_,h3_);
    *(ull*)&wldsL[us] = pack4(l0_,l1_,l2_,l3_);
  }

  int b = t&63, cc = t>>6;
  int hc = jj4 + cc;
  int lane = t&63, w = t>>6, w16 = w*16;
  int l15 = lane&15, l7 = lane&7, kg = lane>>4;
  int hreg = w*4096;

  float creg = c0[b*NH + hc];
  hvals[b][cc] = h0[b*NH + hc];
  __syncthreads();
  {
    int sb = t&63, which = t>>6;
    if (which<2){
      float v0=hvals[sb][0], v1=hvals[sb][1], v2=hvals[sb][2], v3=hvals[sb][3];
      unsigned short u0=f2bf(v0), u1=f2bf(v1), u2=f2bf(v2), u3=f2bf(v3);
      ull pv = (which==0) ? pack4(u0,u1,u2,u3)
             : pack4(f2bf(v0-bf2f(u0)), f2bf(v1-bf2f(u1)),
                     f2bf(v2-bf2f(u2)), f2bf(v3-bf2f(u3)));
      unsigned short* pl = (which==0) ? hbH : hbL;
      __hip_atomic_store((ull*)&pl[(size_t)sb*1024 + jj4], pv,
                         __ATOMIC_RELAXED, __HIP_MEMORY_SCOPE_AGENT);
    }
  }
  unsigned ep = 1;
  gbar(flags, ep); ep++;

  for (int st=0; st<TSTEPS; st++){
    const size_t hsrc  = (size_t)(st&1)*65536;
    const size_t hdstg = (size_t)((st+1)&1)*65536;

    float gtv0 = GT[((size_t)0*NH + jj4 + cc)*NN + st*64 + b];
    float gtv1 = GT[((size_t)1*NH + jj4 + cc)*NN + st*64 + b];
    float gtv2 = GT[((size_t)2*NH + jj4 + cc)*NN + st*64 + b];
    float gtv3 = GT[((size_t)3*NH + jj4 + cc)*NN + st*64 + b];
    __builtin_amdgcn_sched_barrier(0);

    f32x4 accA = {0.f,0.f,0.f,0.f};
    f32x4 accB = {0.f,0.f,0.f,0.f};
    f32x4 accC = {0.f,0.f,0.f,0.f};

    ISSUE_CHUNK(0,0); ISSUE_CHUNK(1,1); ISSUE_CHUNK(2,2);
    for (int c=0;c<13;c++){
      ISSUE_CHUNK(c+3, (c+3)&3);
      WAITVM(12);
      COMPUTE_CHUNK(c, c&3);
    }
    WAITVM(8);  COMPUTE_CHUNK(13,1);
    WAITVM(4);  COMPUTE_CHUNK(14,2);
    WAITVM(0);  COMPUTE_CHUNK(15,3);

    glds[w16 + l15][kg*4+0] = accA[0]+accB[0]+accC[0];
    glds[w16 + l15][kg*4+1] = accA[1]+accB[1]+accC[1];
    glds[w16 + l15][kg*4+2] = accA[2]+accB[2]+accC[2];
    glds[w16 + l15][kg*4+3] = accA[3]+accB[3]+accC[3];
    __syncthreads();
    float gi = glds[b][0 +cc] + gtv0;
    float gf = glds[b][4 +cc] + gtv1;
    float gg = glds[b][8 +cc] + gtv2;
    float go = glds[b][12+cc] + gtv3;
    float cnew = sigmf(gf)*creg + sigmf(gi)*tanhf(gg);
    creg = cnew;
    float hv = sigmf(go)*tanhf(cnew);
    hvals[b][cc] = hv;
    if (st == TSTEPS-1){ hN[b*NH+hc] = hv; cN[b*NH+hc] = creg; }
    __syncthreads();
    {
      int sb = t&63, which = t>>6;
      if (which<2){
        float v0=hvals[sb][0], v1=hvals[sb][1], v2=hvals[sb][2], v3=hvals[sb][3];
        unsigned short u0=f2bf(v0), u1=f2bf(v1), u2=f2bf(v2), u3=f2bf(v3);
        ull pv = (which==0) ? pack4(u0,u1,u2,u3)
               : pack4(f2bf(v0-bf2f(u0)), f2bf(v1-bf2f(u1)),
                       f2bf(v2-bf2f(u2)), f2bf(v3-bf2f(u3)));
        unsigned short* pl = (which==0) ? hbH : hbL;
        __hip_atomic_store((ull*)&pl[hdstg + (size_t)sb*1024 + jj4], pv,
                           __ATOMIC_RELAXED, __HIP_MEMORY_SCOPE_AGENT);
      } else if (which==2){
        float4 yv = make_float4(hvals[sb][0],hvals[sb][1],hvals[sb][2],hvals[sb][3]);
        *(float4*)(Y + (size_t)(st*BB+sb)*NH + jj4) = yv;
      }
    }
    gbar(flags, ep); ep++;
  }
}

// ---------------- top logits ----------------
__global__ __launch_bounds__(256) void k_gemm_top(
    const float* __restrict__ X, const float* __restrict__ W,
    const float* __restrict__ bias, float* __restrict__ C)
{
  __shared__ float Xs[32][68];
  __shared__ float Ws[32][36];
  int n0 = blockIdx.x*64, c0 = blockIdx.y*32;
  int t = threadIdx.x;
  int tm = (t&15)*4;
  int tn = (t>>4)*2;
  int lr = t>>3, lk = (t&7)*4;
  float acc[4][2] = {{0.f}};
  for (int k0=0;k0<NH;k0+=32){
    float4 x0 = *(const float4*)(X + (size_t)(n0+lr)*NH + k0+lk);
    float4 x1 = *(const float4*)(X + (size_t)(n0+lr+32)*NH + k0+lk);
    float4 wv = *(const float4*)(W + (size_t)(k0 + (t>>3))*NCLS + c0 + (t&7)*4);
    __syncthreads();
    Xs[lk+0][lr]=x0.x; Xs[lk+1][lr]=x0.y; Xs[lk+2][lr]=x0.z; Xs[lk+3][lr]=x0.w;
    Xs[lk+0][lr+32]=x1.x; Xs[lk+1][lr+32]=x1.y; Xs[lk+2][lr+32]=x1.z; Xs[lk+3][lr+32]=x1.w;
    *(float4*)&Ws[t>>3][(t&7)*4] = wv;
    __syncthreads();
    #pragma unroll 8
    for (int kk=0;kk<32;kk++){
      float4 av = *(const float4*)&Xs[kk][tm];
      float2 bv = *(const float2*)&Ws[kk][tn];
      acc[0][0] += av.x*bv.x; acc[0][1] += av.x*bv.y;
      acc[1][0] += av.y*bv.x; acc[1][1] += av.y*bv.y;
      acc[2][0] += av.z*bv.x; acc[2][1] += av.z*bv.y;
      acc[3][0] += av.w*bv.x; acc[3][1] += av.w*bv.y;
    }
  }
  float bz0 = bias[c0+tn], bz1 = bias[c0+tn+1];
  #pragma unroll
  for (int i=0;i<4;i++){
    float2 o = make_float2(acc[i][0]+bz0, acc[i][1]+bz1);
    *(float2*)(C + (size_t)(n0+tm+i)*NCLS + c0+tn) = o;
  }
}

// ---------------- per-row top softmax pick ----------------
__global__ void k_top_pick(const float* __restrict__ TL, const int* __restrict__ tg,
                           float* __restrict__ ptop){
  int n = blockIdx.x*4 + (threadIdx.x>>6);
  int lane = threadIdx.x&63;
  const float* row = TL + (size_t)n*NCLS;
  float v[4]; float m = -1e30f;
  #pragma unroll
  for (int q=0;q<4;q++){ int c = lane + q*64; v[q] = (c<NCLS)? row[c] : -1e30f; m = fmaxf(m, v[q]); }
  for (int o=32;o;o>>=1) m = fmaxf(m, __shfl_xor(m,o));
  float s = 0.f;
  #pragma unroll
  for (int q=0;q<4;q++){ int c = lane + q*64; if (c<NCLS) s += expf(v[q]-m); }
  for (int o=32;o;o>>=1) s += __shfl_xor(s,o);
  if (lane==0){ int pt = tg[n]/NPC; ptop[n] = expf(row[pt]-m)/s; }
}

// ---------------- class bucketing ----------------
__global__ void k_zero(int* cnt, int* cur){ int t=threadIdx.x; if(t<NCLS){cnt[t]=0; cur[t]=0;} }
__global__ void k_hist(const int* __restrict__ tg, int* cnt){
  int n = blockIdx.x*256+threadIdx.x;
  if (n<NN) atomicAdd(&cnt[tg[n]/NPC],1);
}
__global__ void k_scan(const int* __restrict__ cnt, int* __restrict__ off){
  if (threadIdx.x==0 && blockIdx.x==0){ int a=0; for(int c=0;c<NCLS;c++){ off[c]=a; a+=cnt[c]; } off[NCLS]=a; }
}
__global__ void k_scatter(const int* __restrict__ tg, const int* __restrict__ off,
                          int* cur, int* __restrict__ perm){
  int n = blockIdx.x*256+threadIdx.x;
  if (n<NN){ int c = tg[n]/NPC; int p = atomicAdd(&cur[c],1); perm[off[c]+p] = n; }
}

// ---------------- per-class bottom GEMM + softmax pick + final product ----------------
__global__ __launch_bounds__(256) void k_bot(
    const float* __restrict__ X, const float* __restrict__ botW, const float* __restrict__ botb,
    const int* __restrict__ tg, const int* __restrict__ off, const int* __restrict__ perm,
    const float* __restrict__ ptop, float* __restrict__ outP)
{
  int cls = blockIdx.x;
  int s = off[cls], e = off[cls+1];
  if (s>=e) return;
  __shared__ float xs[16][NH];
  __shared__ float lg[16][228];
  int t = threadIdx.x;
  const float* Wc = botW + (size_t)cls*NH*NPC;
  for (int base=s; base<e; base+=16){
    int nr = min(16, e-base);
    __syncthreads();
    for (int r=0;r<nr;r++){
      int n = perm[base+r];
      *(float4*)&xs[r][t*4] = *(const float4*)(X + (size_t)n*NH + t*4);
    }
    __syncthreads();
    if (t < NPC){
      float acc[16];
      #pragma unroll
      for (int r=0;r<16;r++) acc[r]=0.f;
      for (int k=0;k<NH;k+=2){
        float w0 = Wc[(size_t)k*NPC + t];
        float w1 = Wc[(size_t)(k+1)*NPC + t];
        #pragma unroll
        for (int r=0;r<16;r++){
          float2 x2 = *(const float2*)&xs[r][k];
          acc[r] += x2.x*w0 + x2.y*w1;
        }
      }
      float bb = botb[(size_t)cls*NPC + t];
      for (int r=0;r<nr;r++) lg[r][t] = acc[r] + bb;
    }
    __syncthreads();
    int wv = t>>6, lane = t&63;
    for (int r=wv; r<nr; r+=4){
      float v[4]; float m=-1e30f;
      #pragma unroll
      for (int q=0;q<4;q++){ int c = lane+q*64; v[q] = (c<NPC)? lg[r][c] : -1e30f; m=fmaxf(m,v[q]); }
      for (int o=32;o;o>>=1) m=fmaxf(m,__shfl_xor(m,o));
      float ss=0.f;
      #pragma unroll
      for (int q=0;q<4;q++){ int c = lane+q*64; if (c<NPC) ss += expf(v[q]-m); }
      for (int o=32;o;o>>=1) ss += __shfl_xor(ss,o);
      if (lane==0){
        int n = perm[base+r]; int pb = tg[n]%NPC;
        outP[n] = ptop[n]*expf(lg[r][pb]-m)/ss;
      }
    }
  }
}

extern "C" void kernel_launch(void* const* d_in, const int* in_sizes, int n_in,
                              void* d_out, int out_size, void* d_ws, size_t ws_size,
                              hipStream_t stream)
{
  const int*   ids  = (const int*)d_in[0];
  const int*   tg   = (const int*)d_in[1];
  const float* h0   = (const float*)d_in[2];
  const float* c0   = (const float*)d_in[3];
  const float* embW = (const float*)d_in[4];
  const float* Wih  = (const float*)d_in[5];
  const float* Whh  = (const float*)d_in[6];
  const float* bih  = (const float*)d_in[7];
  const float* bhh  = (const float*)d_in[8];
  const float* topW = (const float*)d_in[9];
  const float* topb = (const float*)d_in[10];
  const float* botW = (const float*)d_in[11];
  const float* botb = (const float*)d_in[12];
  float* out = (float*)d_out;

  float* X  = (float*)d_ws;                    // 8M floats
  float* Yb = X  + (size_t)NN*NH;              // 8M
  float* GT = Yb + (size_t)NN*NH;              // 32M
  unsigned short* BhP = (unsigned short*)(GT + (size_t)G4*NN);  // 8M ush
  unsigned short* BlP = BhP + (size_t)NN*NH;                     // 8M ush
  unsigned short* WhP = BlP + (size_t)NN*NH;                     // 4M ush
  unsigned short* WlP = WhP + (size_t)G4*NH;                     // 4M ush
  unsigned short* hbH = WlP + (size_t)G4*NH;   // [2][64][1024]
  unsigned short* hbL = hbH + 2*BB*NH;
  float* TL = (float*)(hbL + 2*BB*NH);         // [NN][NCLS]
  float* pt = TL + (size_t)NN*NCLS;
  int* cnt  = (int*)(pt + NN);
  int* off  = cnt + NCLS;
  int* cur  = off + NCLS + 1;
  int* perm = cur + NCLS;
  unsigned* flags = (unsigned*)(perm + NN);

  k_embed<<<NN,256,0,stream>>>(ids, embW, X);

  for (int l=0; l<2; l++){
    const float* A   = Wih + (size_t)l*G4*NH;
    const float* Wl  = Whh + (size_t)l*G4*NH;
    const float* bi  = bih + (size_t)l*G4;
    const float* bh  = bhh + (size_t)l*G4;
    const float* Bx  = (l==0)? X : Yb;
    float*       Yo  = (l==0)? Yb : X;
    // fp32 -> bf16 hi/lo planes
    k_cvt<<<(G4*NH/8)/256,256,0,stream>>>(A,  WhP, WlP);
    k_cvt<<<(NN*NH/8)/256,256,0,stream>>>(Bx, BhP, BlP);
    // split-bf16 MFMA input GEMM
    k_gemm3<<<dim3(G4/128, NN/128),256,0,stream>>>(WhP, WlP, BhP, BlP, bi, bh, GT);
    const float* h0l = h0 + (size_t)l*BB*NH;
    const float* c0l = c0 + (size_t)l*BB*NH;
    float* hNl = out + NN + (size_t)l*BB*NH;
    float* cNl = out + NN + 2*(size_t)BB*NH + (size_t)l*BB*NH;
    (void)hipMemsetAsync(flags, 0, 256*sizeof(unsigned), stream);
    k_rec<<<256,256,0,stream>>>(GT, Wl, h0l, c0l, hbH, hbL, Yo, hNl, cNl, flags);
  }

  // X now holds the layer-1 output sequence [NN][NH]
  k_gemm_top<<<dim3(128,7),256,0,stream>>>(X, topW, topb, TL);
  k_top_pick<<<NN/4,256,0,stream>>>(TL, tg, pt);
  k_zero<<<1,256,0,stream>>>(cnt, cur);
  k_hist<<<NN/256,256,0,stream>>>(tg, cnt);
  k_scan<<<1,1,0,stream>>>(cnt, off);
  k_scatter<<<NN/256,256,0,stream>>>(tg, off, cur, perm);
  k_bot<<<NCLS,256,0,stream>>>(X, botW, botb, tg, off, perm, pt, out);
}